// Round 1
// baseline (932.321 us; speedup 1.0000x reference)
//
#include <hip/hip_runtime.h>
#include <hip/hip_bf16.h>
#include <math.h>

#define IN_CH 512
#define MID_CH 64
#define OUT_CH 40

typedef __attribute__((ext_vector_type(8))) short short8;
typedef __attribute__((ext_vector_type(4))) float f32x4;

static __device__ __forceinline__ unsigned short f2bf(float f) {
    unsigned int u = __float_as_uint(f);
    u += 0x7fffu + ((u >> 16) & 1u);   // round-to-nearest-even on bf16 boundary
    return (unsigned short)(u >> 16);
}

// ---------------- degree count ----------------
__global__ void k_count(const int* __restrict__ dst, int* __restrict__ cnt, int E) {
    int i = blockIdx.x * blockDim.x + threadIdx.x;
    if (i < E) atomicAdd(&cnt[dst[i]], 1);
}

__global__ void k_dis(const int* __restrict__ cnt, float* __restrict__ dis, int N) {
    int i = blockIdx.x * blockDim.x + threadIdx.x;
    if (i < N) dis[i] = rsqrtf((float)cnt[i] + 1.0f);
}

// ---------------- GEMM1: h1 = X @ W1  (bf16 MFMA 16x16x32) ----------------
// Block: 256 thr = 4 waves; block covers 64 rows x 64 cols; wave w: rows base+16w..+15.
// W1 staged in LDS as bf16, chunked [ktile(64)][col(64)][8k] so b-frag reads are
// contiguous ds_read_b128 per 16-lane group.
__launch_bounds__(256)
__global__ void k_gemm1(const float* __restrict__ X, const float* __restrict__ W1,
                        float* __restrict__ h1, int N) {
    __shared__ __align__(16) unsigned short wlds[IN_CH * MID_CH]; // 64 KB
    for (int f = threadIdx.x; f < IN_CH * MID_CH; f += 256) {
        int k = f >> 6, c = f & 63;              // W1 is [512][64] row-major
        wlds[(((k >> 3) * 64) + c) * 8 + (k & 7)] = f2bf(W1[f]);
    }
    __syncthreads();

    int wave = threadIdx.x >> 6, lane = threadIdx.x & 63;
    int rbase = blockIdx.x * 64 + wave * 16;
    int g = lane >> 4;                            // k-group 0..3
    int arow = rbase + (lane & 15);
    if (arow > N - 1) arow = N - 1;               // clamp loads; stores are guarded
    const float* xp = X + (size_t)arow * IN_CH + g * 8;

    f32x4 acc[4];
    #pragma unroll
    for (int i = 0; i < 4; ++i) acc[i] = (f32x4){0.f, 0.f, 0.f, 0.f};

    #pragma unroll 4
    for (int ks = 0; ks < 16; ++ks) {
        const float4* a4 = (const float4*)(xp + ks * 32);
        float4 x0 = a4[0];
        float4 x1 = a4[1];
        short8 a;
        a[0] = (short)f2bf(x0.x); a[1] = (short)f2bf(x0.y);
        a[2] = (short)f2bf(x0.z); a[3] = (short)f2bf(x0.w);
        a[4] = (short)f2bf(x1.x); a[5] = (short)f2bf(x1.y);
        a[6] = (short)f2bf(x1.z); a[7] = (short)f2bf(x1.w);

        int cibase = (ks * 4 + g) * 64 + (lane & 15);
        #pragma unroll
        for (int ct = 0; ct < 4; ++ct) {
            short8 b = *((const short8*)(wlds + (size_t)(cibase + ct * 16) * 8));
            acc[ct] = __builtin_amdgcn_mfma_f32_16x16x32_bf16(a, b, acc[ct], 0, 0, 0);
        }
    }

    // D layout: col = lane&15, row = (lane>>4)*4 + reg
    int colb = lane & 15;
    int rquad = rbase + (lane >> 4) * 4;
    #pragma unroll
    for (int ct = 0; ct < 4; ++ct) {
        #pragma unroll
        for (int r = 0; r < 4; ++r) {
            int row = rquad + r;
            if (row < N) h1[(size_t)row * 64 + ct * 16 + colb] = acc[ct][r];
        }
    }
}

// ---------------- edge scatter: S[dst] += dis[src] * h[src]  (64 ch / edge) --------
__launch_bounds__(256)
__global__ void k_scatter(const float* __restrict__ h, const float* __restrict__ dis,
                          const int* __restrict__ src, const int* __restrict__ dst,
                          float* __restrict__ S, int E) {
    int e = blockIdx.x * 4 + (threadIdx.x >> 6);
    int lane = threadIdx.x & 63;
    if (e >= E) return;
    int s = src[e], d = dst[e];
    float v = dis[s] * h[(size_t)s * 64 + lane];
    atomicAdd(&S[(size_t)d * 64 + lane], v);
}

// ---------------- finish layer 1: h = elu(dis*S + dis^2*h1 + b1); re-zero S -------
__global__ void k_finish1(float* __restrict__ h1, float* __restrict__ S,
                          const float* __restrict__ dis, const float* __restrict__ b1,
                          int N) {
    int idx = blockIdx.x * blockDim.x + threadIdx.x;
    if (idx >= N * MID_CH) return;
    int n = idx >> 6, c = idx & 63;
    float dn = dis[n];
    float v = dn * S[idx] + dn * dn * h1[idx] + b1[c];
    h1[idx] = v > 0.f ? v : expm1f(v);
    S[idx] = 0.f;                 // clean for layer-2 scatter (within this call)
}

// ---------------- finish layer 2: out = log_softmax((dis*S + dis^2*h) @ W2 + b2) --
__launch_bounds__(256)
__global__ void k_finish2(const float* __restrict__ h, const float* __restrict__ S,
                          const float* __restrict__ dis, const float* __restrict__ W2,
                          const float* __restrict__ b2, float* __restrict__ out, int N) {
    __shared__ float w2l[MID_CH * OUT_CH + 64];  // +pad: lanes >=40 read garbage, masked
    __shared__ float b2l[OUT_CH];
    __shared__ float vl[4 * MID_CH];
    for (int f = threadIdx.x; f < MID_CH * OUT_CH; f += 256) w2l[f] = W2[f];
    if (threadIdx.x < OUT_CH) b2l[threadIdx.x] = b2[threadIdx.x];
    __syncthreads();

    int wv = threadIdx.x >> 6, lane = threadIdx.x & 63;
    int n = blockIdx.x * 4 + wv;
    if (n >= N) return;
    float dn = dis[n];
    float v = dn * S[(size_t)n * 64 + lane] + dn * dn * h[(size_t)n * 64 + lane];
    vl[wv * 64 + lane] = v;      // wave-local exchange; LDS ops in-wave are ordered

    float acc = (lane < OUT_CH) ? b2l[lane] : 0.f;
    const float* vrow = &vl[wv * 64];
    #pragma unroll 8
    for (int c = 0; c < MID_CH; ++c)
        acc += vrow[c] * w2l[c * OUT_CH + lane];

    float m = (lane < OUT_CH) ? acc : -1e30f;
    #pragma unroll
    for (int o = 32; o > 0; o >>= 1) m = fmaxf(m, __shfl_xor(m, o));
    float e = (lane < OUT_CH) ? expf(acc - m) : 0.f;
    float ssum = e;
    #pragma unroll
    for (int o = 32; o > 0; o >>= 1) ssum += __shfl_xor(ssum, o);
    if (lane < OUT_CH)
        out[(size_t)n * OUT_CH + lane] = acc - m - logf(ssum);
}

extern "C" void kernel_launch(void* const* d_in, const int* in_sizes, int n_in,
                              void* d_out, int out_size, void* d_ws, size_t ws_size,
                              hipStream_t stream) {
    const float* X  = (const float*)d_in[0];
    const int* adj  = (const int*)d_in[1];
    const float* W1 = (const float*)d_in[2];
    const float* b1 = (const float*)d_in[3];
    const float* W2 = (const float*)d_in[4];
    const float* b2 = (const float*)d_in[5];
    float* out = (float*)d_out;

    int N = in_sizes[0] / IN_CH;
    int E = in_sizes[1] / 2;
    const int* srcp = adj;
    const int* dstp = adj + E;

    char* ws = (char*)d_ws;
    size_t off = 0;
    int*   cnt = (int*)(ws + off);   off += (size_t)N * sizeof(int);
    float* dis = (float*)(ws + off); off += (size_t)N * sizeof(float);
    float* h1  = (float*)(ws + off); off += (size_t)N * MID_CH * sizeof(float);
    float* S   = (float*)(ws + off); off += (size_t)N * MID_CH * sizeof(float);

    hipMemsetAsync(cnt, 0, (size_t)N * sizeof(int), stream);
    hipMemsetAsync(S, 0, (size_t)N * MID_CH * sizeof(float), stream);

    k_count<<<(E + 255) / 256, 256, 0, stream>>>(dstp, cnt, E);
    k_dis<<<(N + 255) / 256, 256, 0, stream>>>(cnt, dis, N);
    k_gemm1<<<(N + 63) / 64, 256, 0, stream>>>(X, W1, h1, N);
    k_scatter<<<(E + 3) / 4, 256, 0, stream>>>(h1, dis, srcp, dstp, S, E);
    k_finish1<<<(N * MID_CH + 255) / 256, 256, 0, stream>>>(h1, S, dis, b1, N);
    k_scatter<<<(E + 3) / 4, 256, 0, stream>>>(h1, dis, srcp, dstp, S, E);
    k_finish2<<<(N + 3) / 4, 256, 0, stream>>>(h1, S, dis, W2, b2, out, N);
}

// Round 2
// 511.829 us; speedup vs baseline: 1.8215x; 1.8215x over previous
//
#include <hip/hip_runtime.h>
#include <hip/hip_bf16.h>
#include <math.h>

#define IN_CH 512
#define MID_CH 64
#define OUT_CH 40

typedef __attribute__((ext_vector_type(8))) short short8;
typedef __attribute__((ext_vector_type(4))) float f32x4;

static __device__ __forceinline__ unsigned short f2bf(float f) {
    unsigned int u = __float_as_uint(f);
    u += 0x7fffu + ((u >> 16) & 1u);   // round-to-nearest-even on bf16 boundary
    return (unsigned short)(u >> 16);
}

// ---------------- degree count ----------------
__global__ void k_count(const int* __restrict__ dst, int* __restrict__ cnt, int E) {
    int i = blockIdx.x * blockDim.x + threadIdx.x;
    if (i < E) atomicAdd(&cnt[dst[i]], 1);
}

// ---------------- CSR scan: rowptr = exclusive_scan(cnt), plus dis = rsqrt(cnt+1) ----
// A: per-1024-chunk inclusive scan (wave shfl + LDS combine), chunk totals to bsum
__global__ void k_scanA(const int* __restrict__ cnt, int* __restrict__ rowptr,
                        int* __restrict__ bsum, float* __restrict__ dis, int N) {
    __shared__ int wsum[16];
    int i = blockIdx.x * 1024 + threadIdx.x;
    int lane = threadIdx.x & 63, wv = threadIdx.x >> 6;
    int v = (i < N) ? cnt[i] : 0;
    if (i < N) dis[i] = rsqrtf((float)v + 1.0f);
    int x = v;
    #pragma unroll
    for (int off = 1; off < 64; off <<= 1) {
        int t = __shfl_up(x, off);
        if (lane >= off) x += t;
    }
    if (lane == 63) wsum[wv] = x;
    __syncthreads();
    if (wv == 0 && lane < 16) {
        int own = wsum[lane];
        int y = own;
        #pragma unroll
        for (int off = 1; off < 16; off <<= 1) {
            int t = __shfl_up(y, off);
            if (lane >= off) y += t;
        }
        wsum[lane] = y - own;                 // exclusive wave offset
        if (lane == 15) bsum[blockIdx.x] = y; // chunk total
    }
    __syncthreads();
    if (i < N) rowptr[i + 1] = x + wsum[wv];
}

// B: exclusive scan of chunk totals (nb <= 128)
__global__ void k_scanB(int* __restrict__ bsum, int nb) {
    __shared__ int tmp[2];
    int lane = threadIdx.x & 63, wv = threadIdx.x >> 6;
    int v = (threadIdx.x < nb) ? bsum[threadIdx.x] : 0;
    int x = v;
    #pragma unroll
    for (int off = 1; off < 64; off <<= 1) {
        int t = __shfl_up(x, off);
        if (lane >= off) x += t;
    }
    if (lane == 63) tmp[wv] = x;
    __syncthreads();
    int add = (wv == 1) ? tmp[0] : 0;
    if (threadIdx.x < nb) bsum[threadIdx.x] = x - v + add;
}

// C: add chunk offsets, set rowptr[0]
__global__ void k_scanC(int* __restrict__ rowptr, const int* __restrict__ bsum, int N) {
    int i = blockIdx.x * 1024 + threadIdx.x;
    if (i < N) rowptr[i + 1] += bsum[blockIdx.x];
    if (i == 0) rowptr[0] = 0;
}

// ---------------- fill CSR edge array (src indices grouped by dst) ----------------
__global__ void k_fill(const int* __restrict__ src, const int* __restrict__ dst,
                       const int* __restrict__ rowptr, int* __restrict__ cur,
                       int* __restrict__ esrc, int E) {
    int e = blockIdx.x * blockDim.x + threadIdx.x;
    if (e < E) {
        int d = dst[e];
        int p = rowptr[d] + atomicAdd(&cur[d], 1);
        esrc[p] = src[e];
    }
}

// ---------------- GEMM1: h1 = X @ W1  (bf16 MFMA 16x16x32) ----------------
__launch_bounds__(256)
__global__ void k_gemm1(const float* __restrict__ X, const float* __restrict__ W1,
                        float* __restrict__ h1, int N) {
    __shared__ __align__(16) unsigned short wlds[IN_CH * MID_CH]; // 64 KB
    for (int f = threadIdx.x; f < IN_CH * MID_CH; f += 256) {
        int k = f >> 6, c = f & 63;              // W1 is [512][64] row-major
        wlds[(((k >> 3) * 64) + c) * 8 + (k & 7)] = f2bf(W1[f]);
    }
    __syncthreads();

    int wave = threadIdx.x >> 6, lane = threadIdx.x & 63;
    int rbase = blockIdx.x * 64 + wave * 16;
    int g = lane >> 4;                            // k-group 0..3
    int arow = rbase + (lane & 15);
    if (arow > N - 1) arow = N - 1;               // clamp loads; stores are guarded
    const float* xp = X + (size_t)arow * IN_CH + g * 8;

    f32x4 acc[4];
    #pragma unroll
    for (int i = 0; i < 4; ++i) acc[i] = (f32x4){0.f, 0.f, 0.f, 0.f};

    #pragma unroll 4
    for (int ks = 0; ks < 16; ++ks) {
        const float4* a4 = (const float4*)(xp + ks * 32);
        float4 x0 = a4[0];
        float4 x1 = a4[1];
        short8 a;
        a[0] = (short)f2bf(x0.x); a[1] = (short)f2bf(x0.y);
        a[2] = (short)f2bf(x0.z); a[3] = (short)f2bf(x0.w);
        a[4] = (short)f2bf(x1.x); a[5] = (short)f2bf(x1.y);
        a[6] = (short)f2bf(x1.z); a[7] = (short)f2bf(x1.w);

        int cibase = (ks * 4 + g) * 64 + (lane & 15);
        #pragma unroll
        for (int ct = 0; ct < 4; ++ct) {
            short8 b = *((const short8*)(wlds + (size_t)(cibase + ct * 16) * 8));
            acc[ct] = __builtin_amdgcn_mfma_f32_16x16x32_bf16(a, b, acc[ct], 0, 0, 0);
        }
    }

    // D layout: col = lane&15, row = (lane>>4)*4 + reg
    int colb = lane & 15;
    int rquad = rbase + (lane >> 4) * 4;
    #pragma unroll
    for (int ct = 0; ct < 4; ++ct) {
        #pragma unroll
        for (int r = 0; r < 4; ++r) {
            int row = rquad + r;
            if (row < N) h1[(size_t)row * 64 + ct * 16 + colb] = acc[ct][r];
        }
    }
}

// ---------------- layer 1: gather-aggregate + finish + elu (one wave per node) -----
__launch_bounds__(256)
__global__ void k_agg1(const float* __restrict__ h1, const float* __restrict__ dis,
                       const int* __restrict__ rowptr, const int* __restrict__ esrc,
                       const float* __restrict__ b1, float* __restrict__ h2, int N) {
    int wv = threadIdx.x >> 6, lane = threadIdx.x & 63;
    int n = blockIdx.x * 4 + wv;
    if (n >= N) return;
    int beg = rowptr[n], end = rowptr[n + 1];
    float acc = 0.f;
    for (int cbeg = beg; cbeg < end; cbeg += 64) {
        int m = end - cbeg; if (m > 64) m = 64;
        int sl = (lane < m) ? esrc[cbeg + lane] : 0;
        float dl = (lane < m) ? dis[sl] : 0.f;
        for (int k = 0; k < m; ++k) {
            int s = __shfl(sl, k);
            float ds_ = __shfl(dl, k);
            acc += ds_ * h1[(size_t)s * 64 + lane];
        }
    }
    float dn = dis[n];
    float v = dn * acc + dn * dn * h1[(size_t)n * 64 + lane] + b1[lane];
    h2[(size_t)n * 64 + lane] = v > 0.f ? v : expm1f(v);
}

// ---------------- layer 2: gather-aggregate + GEMM2 + log_softmax ------------------
__launch_bounds__(256)
__global__ void k_agg2(const float* __restrict__ h2, const float* __restrict__ dis,
                       const int* __restrict__ rowptr, const int* __restrict__ esrc,
                       const float* __restrict__ W2, const float* __restrict__ b2,
                       float* __restrict__ out, int N) {
    __shared__ float w2l[MID_CH * OUT_CH];
    __shared__ float vl[4 * MID_CH];
    for (int f = threadIdx.x; f < MID_CH * OUT_CH; f += 256) w2l[f] = W2[f];
    __syncthreads();

    int wv = threadIdx.x >> 6, lane = threadIdx.x & 63;
    int n = blockIdx.x * 4 + wv;
    if (n >= N) return;
    int beg = rowptr[n], end = rowptr[n + 1];
    float acc = 0.f;
    for (int cbeg = beg; cbeg < end; cbeg += 64) {
        int m = end - cbeg; if (m > 64) m = 64;
        int sl = (lane < m) ? esrc[cbeg + lane] : 0;
        float dl = (lane < m) ? dis[sl] : 0.f;
        for (int k = 0; k < m; ++k) {
            int s = __shfl(sl, k);
            float ds_ = __shfl(dl, k);
            acc += ds_ * h2[(size_t)s * 64 + lane];
        }
    }
    float dn = dis[n];
    float v = dn * acc + dn * dn * h2[(size_t)n * 64 + lane];
    vl[wv * 64 + lane] = v;       // wave-local LDS exchange (in-wave ordering)

    float o = (lane < OUT_CH) ? b2[lane] : 0.f;
    const float* vrow = &vl[wv * 64];
    #pragma unroll 8
    for (int c = 0; c < MID_CH; ++c)
        o += vrow[c] * w2l[c * OUT_CH + lane];

    float mx = (lane < OUT_CH) ? o : -1e30f;
    #pragma unroll
    for (int off = 32; off > 0; off >>= 1) mx = fmaxf(mx, __shfl_xor(mx, off));
    float e = (lane < OUT_CH) ? expf(o - mx) : 0.f;
    float ssum = e;
    #pragma unroll
    for (int off = 32; off > 0; off >>= 1) ssum += __shfl_xor(ssum, off);
    if (lane < OUT_CH)
        out[(size_t)n * OUT_CH + lane] = o - mx - logf(ssum);
}

extern "C" void kernel_launch(void* const* d_in, const int* in_sizes, int n_in,
                              void* d_out, int out_size, void* d_ws, size_t ws_size,
                              hipStream_t stream) {
    const float* X  = (const float*)d_in[0];
    const int* adj  = (const int*)d_in[1];
    const float* W1 = (const float*)d_in[2];
    const float* b1 = (const float*)d_in[3];
    const float* W2 = (const float*)d_in[4];
    const float* b2 = (const float*)d_in[5];
    float* out = (float*)d_out;

    int N = in_sizes[0] / IN_CH;
    int E = in_sizes[1] / 2;
    const int* srcp = adj;
    const int* dstp = adj + E;
    int nchunk = (N + 1023) / 1024;              // 98 for N=100000 (<=128 required)

    char* ws = (char*)d_ws;
    size_t off = 0;
    int*   cnt    = (int*)(ws + off);  off += (size_t)N * sizeof(int);        // also cursor
    float* dis    = (float*)(ws + off); off += (size_t)N * sizeof(float);
    int*   rowptr = (int*)(ws + off);  off += ((size_t)N + 8) * sizeof(int);
    int*   bsum   = (int*)(ws + off);  off += 128 * sizeof(int);
    int*   esrc   = (int*)(ws + off);  off += (size_t)E * sizeof(int);
    float* h1     = (float*)(ws + off); off += (size_t)N * MID_CH * sizeof(float);
    float* h2     = (float*)(ws + off); off += (size_t)N * MID_CH * sizeof(float);

    hipMemsetAsync(cnt, 0, (size_t)N * sizeof(int), stream);
    k_count<<<(E + 255) / 256, 256, 0, stream>>>(dstp, cnt, E);
    k_scanA<<<nchunk, 1024, 0, stream>>>(cnt, rowptr, bsum, dis, N);
    k_scanB<<<1, 128, 0, stream>>>(bsum, nchunk);
    k_scanC<<<nchunk, 1024, 0, stream>>>(rowptr, bsum, N);
    hipMemsetAsync(cnt, 0, (size_t)N * sizeof(int), stream);  // cursor
    k_fill<<<(E + 255) / 256, 256, 0, stream>>>(srcp, dstp, rowptr, cnt, esrc, E);

    k_gemm1<<<(N + 63) / 64, 256, 0, stream>>>(X, W1, h1, N);
    k_agg1<<<(N + 3) / 4, 256, 0, stream>>>(h1, dis, rowptr, esrc, b1, h2, N);
    k_agg2<<<(N + 3) / 4, 256, 0, stream>>>(h2, dis, rowptr, esrc, W2, b2, out, N);
}

// Round 3
// 416.383 us; speedup vs baseline: 2.2391x; 1.2292x over previous
//
#include <hip/hip_runtime.h>
#include <hip/hip_bf16.h>
#include <math.h>

#define IN_CH 512
#define MID_CH 64
#define OUT_CH 40

typedef __attribute__((ext_vector_type(8))) short short8;
typedef __attribute__((ext_vector_type(4))) float f32x4;

static __device__ __forceinline__ unsigned short f2bf(float f) {
    unsigned int u = __float_as_uint(f);
    u += 0x7fffu + ((u >> 16) & 1u);   // round-to-nearest-even on bf16 boundary
    return (unsigned short)(u >> 16);
}

// ---------------- degree count ----------------
__global__ void k_count(const int* __restrict__ dst, int* __restrict__ cnt, int E) {
    int i = blockIdx.x * blockDim.x + threadIdx.x;
    if (i < E) atomicAdd(&cnt[dst[i]], 1);
}

// ---------------- CSR scan over PADDED degrees (round up to 4); dis from real deg ---
__global__ void k_scanA(const int* __restrict__ cnt, int* __restrict__ rowptr,
                        int* __restrict__ bsum, float* __restrict__ dis, int N) {
    __shared__ int wsum[16];
    int i = blockIdx.x * 1024 + threadIdx.x;
    int lane = threadIdx.x & 63, wv = threadIdx.x >> 6;
    int v = (i < N) ? cnt[i] : 0;
    if (i < N) dis[i] = rsqrtf((float)v + 1.0f);
    int x = (v + 3) & ~3;                      // padded degree
    #pragma unroll
    for (int off = 1; off < 64; off <<= 1) {
        int t = __shfl_up(x, off);
        if (lane >= off) x += t;
    }
    if (lane == 63) wsum[wv] = x;
    __syncthreads();
    if (wv == 0 && lane < 16) {
        int own = wsum[lane];
        int y = own;
        #pragma unroll
        for (int off = 1; off < 16; off <<= 1) {
            int t = __shfl_up(y, off);
            if (lane >= off) y += t;
        }
        wsum[lane] = y - own;
        if (lane == 15) bsum[blockIdx.x] = y;
    }
    __syncthreads();
    if (i < N) rowptr[i + 1] = x + wsum[wv];
}

__global__ void k_scanB(int* __restrict__ bsum, int nb) {
    __shared__ int tmp[2];
    int lane = threadIdx.x & 63, wv = threadIdx.x >> 6;
    int v = (threadIdx.x < nb) ? bsum[threadIdx.x] : 0;
    int x = v;
    #pragma unroll
    for (int off = 1; off < 64; off <<= 1) {
        int t = __shfl_up(x, off);
        if (lane >= off) x += t;
    }
    if (lane == 63) tmp[wv] = x;
    __syncthreads();
    int add = (wv == 1) ? tmp[0] : 0;
    if (threadIdx.x < nb) bsum[threadIdx.x] = x - v + add;
}

__global__ void k_scanC(int* __restrict__ rowptr, const int* __restrict__ bsum, int N) {
    int i = blockIdx.x * 1024 + threadIdx.x;
    if (i < N) rowptr[i + 1] += bsum[blockIdx.x];
    if (i == 0) rowptr[0] = 0;
}

// ---------------- init padded esrc slots to dummy-row byte offset ----------------
__global__ void k_padfill(int* __restrict__ esrc, int dummy_off, int total) {
    int i = blockIdx.x * blockDim.x + threadIdx.x;
    if (i < total) esrc[i] = dummy_off;
}

// ---------------- fill CSR with byte offsets (src*128), grouped by dst ------------
__global__ void k_fill(const int* __restrict__ src, const int* __restrict__ dst,
                       const int* __restrict__ rowptr, int* __restrict__ cur,
                       int* __restrict__ esrc, int E) {
    int e = blockIdx.x * blockDim.x + threadIdx.x;
    if (e < E) {
        int d = dst[e];
        int p = rowptr[d] + atomicAdd(&cur[d], 1);
        esrc[p] = src[e] << 7;     // byte offset of 128-B bf16 row
    }
}

// ---------------- GEMM1: h1' = bf16(dis[row] * (X @ W1))  ----------------
__launch_bounds__(256)
__global__ void k_gemm1(const float* __restrict__ X, const float* __restrict__ W1,
                        const float* __restrict__ dis, unsigned short* __restrict__ h1p,
                        int N) {
    __shared__ __align__(16) unsigned short wlds[IN_CH * MID_CH]; // 64 KB
    for (int f = threadIdx.x; f < IN_CH * MID_CH; f += 256) {
        int k = f >> 6, c = f & 63;              // W1 is [512][64] row-major
        wlds[(((k >> 3) * 64) + c) * 8 + (k & 7)] = f2bf(W1[f]);
    }
    __syncthreads();

    int wave = threadIdx.x >> 6, lane = threadIdx.x & 63;
    int rbase = blockIdx.x * 64 + wave * 16;
    int g = lane >> 4;
    int arow = rbase + (lane & 15);
    if (arow > N - 1) arow = N - 1;
    const float* xp = X + (size_t)arow * IN_CH + g * 8;

    f32x4 acc[4];
    #pragma unroll
    for (int i = 0; i < 4; ++i) acc[i] = (f32x4){0.f, 0.f, 0.f, 0.f};

    #pragma unroll 4
    for (int ks = 0; ks < 16; ++ks) {
        const float4* a4 = (const float4*)(xp + ks * 32);
        float4 x0 = a4[0];
        float4 x1 = a4[1];
        short8 a;
        a[0] = (short)f2bf(x0.x); a[1] = (short)f2bf(x0.y);
        a[2] = (short)f2bf(x0.z); a[3] = (short)f2bf(x0.w);
        a[4] = (short)f2bf(x1.x); a[5] = (short)f2bf(x1.y);
        a[6] = (short)f2bf(x1.z); a[7] = (short)f2bf(x1.w);

        int cibase = (ks * 4 + g) * 64 + (lane & 15);
        #pragma unroll
        for (int ct = 0; ct < 4; ++ct) {
            short8 b = *((const short8*)(wlds + (size_t)(cibase + ct * 16) * 8));
            acc[ct] = __builtin_amdgcn_mfma_f32_16x16x32_bf16(a, b, acc[ct], 0, 0, 0);
        }
    }

    // D layout: col = lane&15, row = (lane>>4)*4 + reg
    int colb = lane & 15;
    int rquad = rbase + (lane >> 4) * 4;
    #pragma unroll
    for (int ct = 0; ct < 4; ++ct) {
        #pragma unroll
        for (int r = 0; r < 4; ++r) {
            int row = rquad + r;
            if (row < N)
                h1p[(size_t)row * 64 + ct * 16 + colb] = f2bf(acc[ct][r] * dis[row]);
        }
    }
}

// ---------------- layer 1: gather(4 edges/iter) + finish + elu ---------------------
// lane = (g = lane>>4 edge subgroup, cg = lane&15 channel quad)
__launch_bounds__(256)
__global__ void k_agg1(const unsigned short* __restrict__ hp, const float* __restrict__ dis,
                       const int* __restrict__ rowptr, const int* __restrict__ esrc,
                       const float* __restrict__ b1, unsigned short* __restrict__ h2p,
                       int N) {
    int wv = threadIdx.x >> 6, lane = threadIdx.x & 63;
    int n = blockIdx.x * 4 + wv;
    if (n >= N) return;
    int g = lane >> 4, cg = lane & 15;
    int beg = rowptr[n], end = rowptr[n + 1];
    unsigned cgoff = (unsigned)(cg * 8);

    f32x4 acc = (f32x4){0.f, 0.f, 0.f, 0.f};
    for (int cbeg = beg; cbeg < end; cbeg += 64) {
        int m = end - cbeg; if (m > 64) m = 64;          // multiple of 4
        int soff = esrc[cbeg + lane];                    // slack-allocated
        int k4n = m >> 2;
        #pragma unroll 2
        for (int k4 = 0; k4 < k4n; ++k4) {
            int off = __shfl(soff, k4 * 4 + g);
            uint2 u = *(const uint2*)((const char*)hp + ((unsigned)off + cgoff));
            acc[0] += __uint_as_float(u.x << 16);
            acc[1] += __uint_as_float(u.x & 0xffff0000u);
            acc[2] += __uint_as_float(u.y << 16);
            acc[3] += __uint_as_float(u.y & 0xffff0000u);
        }
    }
    #pragma unroll
    for (int off = 32; off >= 16; off >>= 1) {
        acc[0] += __shfl_xor(acc[0], off);
        acc[1] += __shfl_xor(acc[1], off);
        acc[2] += __shfl_xor(acc[2], off);
        acc[3] += __shfl_xor(acc[3], off);
    }
    if (g == 0) {
        float dn = dis[n];
        uint2 us = *(const uint2*)((const char*)hp + ((unsigned)(n * 128) + cgoff));
        float4 b4 = *(const float4*)(b1 + cg * 4);
        float s0 = __uint_as_float(us.x << 16),       s1 = __uint_as_float(us.x & 0xffff0000u);
        float s2 = __uint_as_float(us.y << 16),       s3 = __uint_as_float(us.y & 0xffff0000u);
        float v0 = dn * (acc[0] + s0) + b4.x;
        float v1 = dn * (acc[1] + s1) + b4.y;
        float v2 = dn * (acc[2] + s2) + b4.z;
        float v3 = dn * (acc[3] + s3) + b4.w;
        v0 = v0 > 0.f ? v0 : expm1f(v0);
        v1 = v1 > 0.f ? v1 : expm1f(v1);
        v2 = v2 > 0.f ? v2 : expm1f(v2);
        v3 = v3 > 0.f ? v3 : expm1f(v3);
        uint2 o;
        o.x = (unsigned)f2bf(dn * v0) | ((unsigned)f2bf(dn * v1) << 16);
        o.y = (unsigned)f2bf(dn * v2) | ((unsigned)f2bf(dn * v3) << 16);
        *(uint2*)(h2p + (size_t)n * 64 + cg * 4) = o;
    }
}

// ---------------- layer 2: gather + GEMM2 + log_softmax ---------------------------
__launch_bounds__(256)
__global__ void k_agg2(const unsigned short* __restrict__ hp, const float* __restrict__ dis,
                       const int* __restrict__ rowptr, const int* __restrict__ esrc,
                       const float* __restrict__ W2, const float* __restrict__ b2,
                       float* __restrict__ out, int N) {
    __shared__ float w2l[MID_CH * OUT_CH];
    __shared__ float vl[4 * MID_CH];
    for (int f = threadIdx.x; f < MID_CH * OUT_CH; f += 256) w2l[f] = W2[f];
    __syncthreads();

    int wv = threadIdx.x >> 6, lane = threadIdx.x & 63;
    int n = blockIdx.x * 4 + wv;
    if (n >= N) return;
    int g = lane >> 4, cg = lane & 15;
    int beg = rowptr[n], end = rowptr[n + 1];
    unsigned cgoff = (unsigned)(cg * 8);

    f32x4 acc = (f32x4){0.f, 0.f, 0.f, 0.f};
    for (int cbeg = beg; cbeg < end; cbeg += 64) {
        int m = end - cbeg; if (m > 64) m = 64;
        int soff = esrc[cbeg + lane];
        int k4n = m >> 2;
        #pragma unroll 2
        for (int k4 = 0; k4 < k4n; ++k4) {
            int off = __shfl(soff, k4 * 4 + g);
            uint2 u = *(const uint2*)((const char*)hp + ((unsigned)off + cgoff));
            acc[0] += __uint_as_float(u.x << 16);
            acc[1] += __uint_as_float(u.x & 0xffff0000u);
            acc[2] += __uint_as_float(u.y << 16);
            acc[3] += __uint_as_float(u.y & 0xffff0000u);
        }
    }
    #pragma unroll
    for (int off = 32; off >= 16; off >>= 1) {
        acc[0] += __shfl_xor(acc[0], off);
        acc[1] += __shfl_xor(acc[1], off);
        acc[2] += __shfl_xor(acc[2], off);
        acc[3] += __shfl_xor(acc[3], off);
    }
    if (g == 0) {
        float dn = dis[n];
        uint2 us = *(const uint2*)((const char*)hp + ((unsigned)(n * 128) + cgoff));
        float4 v;
        v.x = dn * (acc[0] + __uint_as_float(us.x << 16));
        v.y = dn * (acc[1] + __uint_as_float(us.x & 0xffff0000u));
        v.z = dn * (acc[2] + __uint_as_float(us.y << 16));
        v.w = dn * (acc[3] + __uint_as_float(us.y & 0xffff0000u));
        *(float4*)&vl[wv * 64 + cg * 4] = v;
    }

    float o = (lane < OUT_CH) ? b2[lane] : 0.f;
    const float* vrow = &vl[wv * 64];
    #pragma unroll 8
    for (int c = 0; c < MID_CH; ++c)
        o += vrow[c] * w2l[c * OUT_CH + lane];

    float mx = (lane < OUT_CH) ? o : -1e30f;
    #pragma unroll
    for (int off = 32; off > 0; off >>= 1) mx = fmaxf(mx, __shfl_xor(mx, off));
    float e = (lane < OUT_CH) ? expf(o - mx) : 0.f;
    float ssum = e;
    #pragma unroll
    for (int off = 32; off > 0; off >>= 1) ssum += __shfl_xor(ssum, off);
    if (lane < OUT_CH)
        out[(size_t)n * OUT_CH + lane] = o - mx - logf(ssum);
}

extern "C" void kernel_launch(void* const* d_in, const int* in_sizes, int n_in,
                              void* d_out, int out_size, void* d_ws, size_t ws_size,
                              hipStream_t stream) {
    const float* X  = (const float*)d_in[0];
    const int* adj  = (const int*)d_in[1];
    const float* W1 = (const float*)d_in[2];
    const float* b1 = (const float*)d_in[3];
    const float* W2 = (const float*)d_in[4];
    const float* b2 = (const float*)d_in[5];
    float* out = (float*)d_out;

    int N = in_sizes[0] / IN_CH;
    int E = in_sizes[1] / 2;
    const int* srcp = adj;
    const int* dstp = adj + E;
    int nchunk = (N + 1023) / 1024;              // 98 (<=128 required)
    int epad_max = E + 3 * N + 128;

    char* ws = (char*)d_ws;
    size_t off = 0;
    int*   cnt    = (int*)(ws + off);  off += (size_t)N * sizeof(int);        // also cursor
    float* dis    = (float*)(ws + off); off += (size_t)N * sizeof(float);
    int*   rowptr = (int*)(ws + off);  off += ((size_t)N + 8) * sizeof(int);
    int*   bsum   = (int*)(ws + off);  off += 128 * sizeof(int);
    int*   esrc   = (int*)(ws + off);  off += (size_t)epad_max * sizeof(int);
    unsigned short* h1p = (unsigned short*)(ws + off); off += (size_t)(N + 2) * MID_CH * sizeof(unsigned short);
    unsigned short* h2p = (unsigned short*)(ws + off); off += (size_t)(N + 2) * MID_CH * sizeof(unsigned short);

    hipMemsetAsync(cnt, 0, (size_t)N * sizeof(int), stream);
    k_count<<<(E + 255) / 256, 256, 0, stream>>>(dstp, cnt, E);
    k_scanA<<<nchunk, 1024, 0, stream>>>(cnt, rowptr, bsum, dis, N);
    k_scanB<<<1, 128, 0, stream>>>(bsum, nchunk);
    k_scanC<<<nchunk, 1024, 0, stream>>>(rowptr, bsum, N);
    k_padfill<<<(epad_max + 255) / 256, 256, 0, stream>>>(esrc, N << 7, epad_max);
    hipMemsetAsync(cnt, 0, (size_t)N * sizeof(int), stream);  // cursor
    k_fill<<<(E + 255) / 256, 256, 0, stream>>>(srcp, dstp, rowptr, cnt, esrc, E);

    // zero dummy row N of both tables (padded edges point here)
    hipMemsetAsync(h1p + (size_t)N * 64, 0, 128, stream);
    hipMemsetAsync(h2p + (size_t)N * 64, 0, 128, stream);

    k_gemm1<<<(N + 63) / 64, 256, 0, stream>>>(X, W1, dis, h1p, N);
    k_agg1<<<(N + 3) / 4, 256, 0, stream>>>(h1p, dis, rowptr, esrc, b1, h2p, N);
    k_agg2<<<(N + 3) / 4, 256, 0, stream>>>(h2p, dis, rowptr, esrc, W2, b2, out, N);
}

// Round 4
// 394.179 us; speedup vs baseline: 2.3652x; 1.0563x over previous
//
#include <hip/hip_runtime.h>
#include <hip/hip_bf16.h>
#include <math.h>

#define IN_CH 512
#define MID_CH 64
#define OUT_CH 40

typedef __attribute__((ext_vector_type(8))) short short8;
typedef __attribute__((ext_vector_type(4))) float f32x4;

static __device__ __forceinline__ unsigned short f2bf(float f) {
    unsigned int u = __float_as_uint(f);
    u += 0x7fffu + ((u >> 16) & 1u);   // round-to-nearest-even on bf16 boundary
    return (unsigned short)(u >> 16);
}

// ---------------- degree count ----------------
__global__ void k_count(const int* __restrict__ dst, int* __restrict__ cnt, int E) {
    int i = blockIdx.x * blockDim.x + threadIdx.x;
    if (i < E) atomicAdd(&cnt[dst[i]], 1);
}

// ---------------- CSR scan over PADDED degrees (round up to 4); dis from real deg ---
__global__ void k_scanA(const int* __restrict__ cnt, int* __restrict__ rowptr,
                        int* __restrict__ bsum, float* __restrict__ dis, int N) {
    __shared__ int wsum[16];
    int i = blockIdx.x * 1024 + threadIdx.x;
    int lane = threadIdx.x & 63, wv = threadIdx.x >> 6;
    int v = (i < N) ? cnt[i] : 0;
    if (i < N) dis[i] = rsqrtf((float)v + 1.0f);
    int x = (v + 3) & ~3;                      // padded degree
    #pragma unroll
    for (int off = 1; off < 64; off <<= 1) {
        int t = __shfl_up(x, off);
        if (lane >= off) x += t;
    }
    if (lane == 63) wsum[wv] = x;
    __syncthreads();
    if (wv == 0 && lane < 16) {
        int own = wsum[lane];
        int y = own;
        #pragma unroll
        for (int off = 1; off < 16; off <<= 1) {
            int t = __shfl_up(y, off);
            if (lane >= off) y += t;
        }
        wsum[lane] = y - own;
        if (lane == 15) bsum[blockIdx.x] = y;
    }
    __syncthreads();
    if (i < N) rowptr[i + 1] = x + wsum[wv];
}

__global__ void k_scanB(int* __restrict__ bsum, int nb) {
    __shared__ int tmp[2];
    int lane = threadIdx.x & 63, wv = threadIdx.x >> 6;
    int v = (threadIdx.x < nb) ? bsum[threadIdx.x] : 0;
    int x = v;
    #pragma unroll
    for (int off = 1; off < 64; off <<= 1) {
        int t = __shfl_up(x, off);
        if (lane >= off) x += t;
    }
    if (lane == 63) tmp[wv] = x;
    __syncthreads();
    int add = (wv == 1) ? tmp[0] : 0;
    if (threadIdx.x < nb) bsum[threadIdx.x] = x - v + add;
}

__global__ void k_scanC(int* __restrict__ rowptr, const int* __restrict__ bsum, int N) {
    int i = blockIdx.x * 1024 + threadIdx.x;
    if (i < N) rowptr[i + 1] += bsum[blockIdx.x];
    if (i == 0) rowptr[0] = 0;
}

// ---------------- init padded esrc slots to dummy-row byte offset ----------------
__global__ void k_padfill(int* __restrict__ esrc, int dummy_off, int total) {
    int i = blockIdx.x * blockDim.x + threadIdx.x;
    if (i < total) esrc[i] = dummy_off;
}

// ---------------- fill CSR with byte offsets (src*128), grouped by dst ------------
__global__ void k_fill(const int* __restrict__ src, const int* __restrict__ dst,
                       const int* __restrict__ rowptr, int* __restrict__ cur,
                       int* __restrict__ esrc, int E) {
    int e = blockIdx.x * blockDim.x + threadIdx.x;
    if (e < E) {
        int d = dst[e];
        int p = rowptr[d] + atomicAdd(&cur[d], 1);
        esrc[p] = src[e] << 7;     // byte offset of 128-B bf16 row
    }
}

// ---------------- prep W1: fp32 [512][64] -> bf16 fragment layout -----------------
// layout: w1f[((k>>3)*64 + c)*8 + (k&7)]  so a 16-lane group's b-frag is one
// contiguous 16B ds_read per (k-chunk, col)
__global__ void k_prepw(const float* __restrict__ W1, unsigned short* __restrict__ w1f) {
    int f = blockIdx.x * 256 + threadIdx.x;      // 32768 total
    int k = f >> 6, c = f & 63;
    w1f[(((k >> 3) * 64) + c) * 8 + (k & 7)] = f2bf(W1[f]);
}

// ---------------- GEMM1: h1' = bf16(dis[row] * (X @ W1))  ----------------
// 512 thr = 8 waves; block = 128 rows x 64 cols; wave w owns rows base+16w..+15.
// W1 staged via linear conflict-free uint4 copy from pre-swizzled w1f.
__launch_bounds__(512, 4)
__global__ void k_gemm1(const float* __restrict__ X, const unsigned short* __restrict__ w1f,
                        const float* __restrict__ dis, unsigned short* __restrict__ h1p,
                        int N) {
    __shared__ __align__(16) unsigned short wlds[IN_CH * MID_CH]; // 64 KB
    {
        const uint4* s4 = (const uint4*)w1f;
        uint4* d4 = (uint4*)wlds;
        #pragma unroll
        for (int i = 0; i < 8; ++i)
            d4[threadIdx.x + i * 512] = s4[threadIdx.x + i * 512];
    }
    __syncthreads();

    int wave = threadIdx.x >> 6, lane = threadIdx.x & 63;
    int rbase = blockIdx.x * 128 + wave * 16;
    int g = lane >> 4;
    int arow = rbase + (lane & 15);
    if (arow > N - 1) arow = N - 1;              // clamp loads; stores are guarded
    const float* xp = X + (size_t)arow * IN_CH + g * 8;

    f32x4 acc[4];
    #pragma unroll
    for (int i = 0; i < 4; ++i) acc[i] = (f32x4){0.f, 0.f, 0.f, 0.f};

    #pragma unroll 4
    for (int ks = 0; ks < 16; ++ks) {
        const float4* a4 = (const float4*)(xp + ks * 32);
        float4 x0 = a4[0];
        float4 x1 = a4[1];
        short8 a;
        a[0] = (short)f2bf(x0.x); a[1] = (short)f2bf(x0.y);
        a[2] = (short)f2bf(x0.z); a[3] = (short)f2bf(x0.w);
        a[4] = (short)f2bf(x1.x); a[5] = (short)f2bf(x1.y);
        a[6] = (short)f2bf(x1.z); a[7] = (short)f2bf(x1.w);

        int cibase = (ks * 4 + g) * 64 + (lane & 15);
        #pragma unroll
        for (int ct = 0; ct < 4; ++ct) {
            short8 b = *((const short8*)(wlds + (size_t)(cibase + ct * 16) * 8));
            acc[ct] = __builtin_amdgcn_mfma_f32_16x16x32_bf16(a, b, acc[ct], 0, 0, 0);
        }
    }

    // D layout: col = lane&15, row = (lane>>4)*4 + reg
    int colb = lane & 15;
    int rquad = rbase + (lane >> 4) * 4;
    #pragma unroll
    for (int ct = 0; ct < 4; ++ct) {
        #pragma unroll
        for (int r = 0; r < 4; ++r) {
            int row = rquad + r;
            if (row < N)
                h1p[(size_t)row * 64 + ct * 16 + colb] = f2bf(acc[ct][r] * dis[row]);
        }
    }
}

// ---------------- layer 1: gather(4 edges/iter) + finish + elu ---------------------
// lane = (g = lane>>4 edge subgroup, cg = lane&15 channel quad)
__launch_bounds__(256)
__global__ void k_agg1(const unsigned short* __restrict__ hp, const float* __restrict__ dis,
                       const int* __restrict__ rowptr, const int* __restrict__ esrc,
                       const float* __restrict__ b1, unsigned short* __restrict__ h2p,
                       int N) {
    int wv = threadIdx.x >> 6, lane = threadIdx.x & 63;
    int n = blockIdx.x * 4 + wv;
    if (n >= N) return;
    int g = lane >> 4, cg = lane & 15;
    int beg = rowptr[n], end = rowptr[n + 1];
    unsigned cgoff = (unsigned)(cg * 8);

    f32x4 acc = (f32x4){0.f, 0.f, 0.f, 0.f};
    for (int cbeg = beg; cbeg < end; cbeg += 64) {
        int m = end - cbeg; if (m > 64) m = 64;          // multiple of 4
        int soff = esrc[cbeg + lane];                    // slack-allocated
        int k4n = m >> 2;
        #pragma unroll 2
        for (int k4 = 0; k4 < k4n; ++k4) {
            int off = __shfl(soff, k4 * 4 + g);
            uint2 u = *(const uint2*)((const char*)hp + ((unsigned)off + cgoff));
            acc[0] += __uint_as_float(u.x << 16);
            acc[1] += __uint_as_float(u.x & 0xffff0000u);
            acc[2] += __uint_as_float(u.y << 16);
            acc[3] += __uint_as_float(u.y & 0xffff0000u);
        }
    }
    #pragma unroll
    for (int off = 32; off >= 16; off >>= 1) {
        acc[0] += __shfl_xor(acc[0], off);
        acc[1] += __shfl_xor(acc[1], off);
        acc[2] += __shfl_xor(acc[2], off);
        acc[3] += __shfl_xor(acc[3], off);
    }
    if (g == 0) {
        float dn = dis[n];
        uint2 us = *(const uint2*)((const char*)hp + ((unsigned)(n * 128) + cgoff));
        float4 b4 = *(const float4*)(b1 + cg * 4);
        float s0 = __uint_as_float(us.x << 16),       s1 = __uint_as_float(us.x & 0xffff0000u);
        float s2 = __uint_as_float(us.y << 16),       s3 = __uint_as_float(us.y & 0xffff0000u);
        float v0 = dn * (acc[0] + s0) + b4.x;
        float v1 = dn * (acc[1] + s1) + b4.y;
        float v2 = dn * (acc[2] + s2) + b4.z;
        float v3 = dn * (acc[3] + s3) + b4.w;
        v0 = v0 > 0.f ? v0 : expm1f(v0);
        v1 = v1 > 0.f ? v1 : expm1f(v1);
        v2 = v2 > 0.f ? v2 : expm1f(v2);
        v3 = v3 > 0.f ? v3 : expm1f(v3);
        uint2 o;
        o.x = (unsigned)f2bf(dn * v0) | ((unsigned)f2bf(dn * v1) << 16);
        o.y = (unsigned)f2bf(dn * v2) | ((unsigned)f2bf(dn * v3) << 16);
        *(uint2*)(h2p + (size_t)n * 64 + cg * 4) = o;
    }
}

// ---------------- layer 2: gather + GEMM2 + log_softmax ---------------------------
__launch_bounds__(256)
__global__ void k_agg2(const unsigned short* __restrict__ hp, const float* __restrict__ dis,
                       const int* __restrict__ rowptr, const int* __restrict__ esrc,
                       const float* __restrict__ W2, const float* __restrict__ b2,
                       float* __restrict__ out, int N) {
    __shared__ float w2l[MID_CH * OUT_CH];
    __shared__ float vl[4 * MID_CH];
    for (int f = threadIdx.x; f < MID_CH * OUT_CH; f += 256) w2l[f] = W2[f];
    __syncthreads();

    int wv = threadIdx.x >> 6, lane = threadIdx.x & 63;
    int n = blockIdx.x * 4 + wv;
    if (n >= N) return;
    int g = lane >> 4, cg = lane & 15;
    int beg = rowptr[n], end = rowptr[n + 1];
    unsigned cgoff = (unsigned)(cg * 8);

    f32x4 acc = (f32x4){0.f, 0.f, 0.f, 0.f};
    for (int cbeg = beg; cbeg < end; cbeg += 64) {
        int m = end - cbeg; if (m > 64) m = 64;
        int soff = esrc[cbeg + lane];
        int k4n = m >> 2;
        #pragma unroll 2
        for (int k4 = 0; k4 < k4n; ++k4) {
            int off = __shfl(soff, k4 * 4 + g);
            uint2 u = *(const uint2*)((const char*)hp + ((unsigned)off + cgoff));
            acc[0] += __uint_as_float(u.x << 16);
            acc[1] += __uint_as_float(u.x & 0xffff0000u);
            acc[2] += __uint_as_float(u.y << 16);
            acc[3] += __uint_as_float(u.y & 0xffff0000u);
        }
    }
    #pragma unroll
    for (int off = 32; off >= 16; off >>= 1) {
        acc[0] += __shfl_xor(acc[0], off);
        acc[1] += __shfl_xor(acc[1], off);
        acc[2] += __shfl_xor(acc[2], off);
        acc[3] += __shfl_xor(acc[3], off);
    }
    if (g == 0) {
        float dn = dis[n];
        uint2 us = *(const uint2*)((const char*)hp + ((unsigned)(n * 128) + cgoff));
        float4 v;
        v.x = dn * (acc[0] + __uint_as_float(us.x << 16));
        v.y = dn * (acc[1] + __uint_as_float(us.x & 0xffff0000u));
        v.z = dn * (acc[2] + __uint_as_float(us.y << 16));
        v.w = dn * (acc[3] + __uint_as_float(us.y & 0xffff0000u));
        *(float4*)&vl[wv * 64 + cg * 4] = v;
    }

    float o = (lane < OUT_CH) ? b2[lane] : 0.f;
    const float* vrow = &vl[wv * 64];
    #pragma unroll 8
    for (int c = 0; c < MID_CH; ++c)
        o += vrow[c] * w2l[c * OUT_CH + lane];

    float mx = (lane < OUT_CH) ? o : -1e30f;
    #pragma unroll
    for (int off = 32; off > 0; off >>= 1) mx = fmaxf(mx, __shfl_xor(mx, off));
    float e = (lane < OUT_CH) ? expf(o - mx) : 0.f;
    float ssum = e;
    #pragma unroll
    for (int off = 32; off > 0; off >>= 1) ssum += __shfl_xor(ssum, off);
    if (lane < OUT_CH)
        out[(size_t)n * OUT_CH + lane] = o - mx - logf(ssum);
}

extern "C" void kernel_launch(void* const* d_in, const int* in_sizes, int n_in,
                              void* d_out, int out_size, void* d_ws, size_t ws_size,
                              hipStream_t stream) {
    const float* X  = (const float*)d_in[0];
    const int* adj  = (const int*)d_in[1];
    const float* W1 = (const float*)d_in[2];
    const float* b1 = (const float*)d_in[3];
    const float* W2 = (const float*)d_in[4];
    const float* b2 = (const float*)d_in[5];
    float* out = (float*)d_out;

    int N = in_sizes[0] / IN_CH;
    int E = in_sizes[1] / 2;
    const int* srcp = adj;
    const int* dstp = adj + E;
    int nchunk = (N + 1023) / 1024;              // 98 (<=128 required)
    int epad_max = E + 3 * N + 128;

    char* ws = (char*)d_ws;
    size_t off = 0;
    int*   cnt    = (int*)(ws + off);  off += (size_t)N * sizeof(int);        // also cursor
    float* dis    = (float*)(ws + off); off += (size_t)N * sizeof(float);
    int*   rowptr = (int*)(ws + off);  off += ((size_t)N + 8) * sizeof(int);
    int*   bsum   = (int*)(ws + off);  off += 128 * sizeof(int);
    int*   esrc   = (int*)(ws + off);  off += (size_t)epad_max * sizeof(int);
    unsigned short* w1f = (unsigned short*)(ws + off); off += (size_t)IN_CH * MID_CH * sizeof(unsigned short);
    unsigned short* h1p = (unsigned short*)(ws + off); off += (size_t)(N + 2) * MID_CH * sizeof(unsigned short);
    unsigned short* h2p = (unsigned short*)(ws + off); off += (size_t)(N + 2) * MID_CH * sizeof(unsigned short);

    hipMemsetAsync(cnt, 0, (size_t)N * sizeof(int), stream);
    k_prepw<<<(IN_CH * MID_CH + 255) / 256, 256, 0, stream>>>(W1, w1f);
    k_count<<<(E + 255) / 256, 256, 0, stream>>>(dstp, cnt, E);
    k_scanA<<<nchunk, 1024, 0, stream>>>(cnt, rowptr, bsum, dis, N);
    k_scanB<<<1, 128, 0, stream>>>(bsum, nchunk);
    k_scanC<<<nchunk, 1024, 0, stream>>>(rowptr, bsum, N);
    k_padfill<<<(epad_max + 255) / 256, 256, 0, stream>>>(esrc, N << 7, epad_max);
    hipMemsetAsync(cnt, 0, (size_t)N * sizeof(int), stream);  // cursor
    k_fill<<<(E + 255) / 256, 256, 0, stream>>>(srcp, dstp, rowptr, cnt, esrc, E);

    // zero dummy row N of both tables (padded edges point here)
    hipMemsetAsync(h1p + (size_t)N * 64, 0, 128, stream);
    hipMemsetAsync(h2p + (size_t)N * 64, 0, 128, stream);

    k_gemm1<<<(N + 127) / 128, 512, 0, stream>>>(X, w1f, dis, h1p, N);
    k_agg1<<<(N + 3) / 4, 256, 0, stream>>>(h1p, dis, rowptr, esrc, b1, h2p, N);
    k_agg2<<<(N + 3) / 4, 256, 0, stream>>>(h2p, dis, rowptr, esrc, W2, b2, out, N);
}

// Round 5
// 383.840 us; speedup vs baseline: 2.4289x; 1.0269x over previous
//
#include <hip/hip_runtime.h>
#include <hip/hip_bf16.h>
#include <math.h>

#define IN_CH 512
#define MID_CH 64
#define OUT_CH 40

typedef __attribute__((ext_vector_type(8))) short short8;
typedef __attribute__((ext_vector_type(4))) float f32x4;

static __device__ __forceinline__ unsigned short f2bf(float f) {
    unsigned int u = __float_as_uint(f);
    u += 0x7fffu + ((u >> 16) & 1u);   // round-to-nearest-even on bf16 boundary
    return (unsigned short)(u >> 16);
}

// ---------------- degree count ----------------
__global__ void k_count(const int* __restrict__ dst, int* __restrict__ cnt, int E) {
    int i = blockIdx.x * blockDim.x + threadIdx.x;
    if (i < E) atomicAdd(&cnt[dst[i]], 1);
}

// ---------------- CSR scan over PADDED degrees (round up to 4); dis from real deg ---
__global__ void k_scanA(const int* __restrict__ cnt, int* __restrict__ rowptr,
                        int* __restrict__ bsum, float* __restrict__ dis, int N) {
    __shared__ int wsum[16];
    int i = blockIdx.x * 1024 + threadIdx.x;
    int lane = threadIdx.x & 63, wv = threadIdx.x >> 6;
    int v = (i < N) ? cnt[i] : 0;
    if (i < N) dis[i] = rsqrtf((float)v + 1.0f);
    int x = (v + 3) & ~3;                      // padded degree
    #pragma unroll
    for (int off = 1; off < 64; off <<= 1) {
        int t = __shfl_up(x, off);
        if (lane >= off) x += t;
    }
    if (lane == 63) wsum[wv] = x;
    __syncthreads();
    if (wv == 0 && lane < 16) {
        int own = wsum[lane];
        int y = own;
        #pragma unroll
        for (int off = 1; off < 16; off <<= 1) {
            int t = __shfl_up(y, off);
            if (lane >= off) y += t;
        }
        wsum[lane] = y - own;
        if (lane == 15) bsum[blockIdx.x] = y;
    }
    __syncthreads();
    if (i < N) rowptr[i + 1] = x + wsum[wv];
}

__global__ void k_scanB(int* __restrict__ bsum, int nb) {
    __shared__ int tmp[2];
    int lane = threadIdx.x & 63, wv = threadIdx.x >> 6;
    int v = (threadIdx.x < nb) ? bsum[threadIdx.x] : 0;
    int x = v;
    #pragma unroll
    for (int off = 1; off < 64; off <<= 1) {
        int t = __shfl_up(x, off);
        if (lane >= off) x += t;
    }
    if (lane == 63) tmp[wv] = x;
    __syncthreads();
    int add = (wv == 1) ? tmp[0] : 0;
    if (threadIdx.x < nb) bsum[threadIdx.x] = x - v + add;
}

__global__ void k_scanC(int* __restrict__ rowptr, const int* __restrict__ bsum, int N) {
    int i = blockIdx.x * 1024 + threadIdx.x;
    if (i < N) rowptr[i + 1] += bsum[blockIdx.x];
    if (i == 0) rowptr[0] = 0;
}

// ---------------- init padded esrc slots to dummy-row byte offset ----------------
__global__ void k_padfill(int* __restrict__ esrc, int dummy_off, int total) {
    int i = blockIdx.x * blockDim.x + threadIdx.x;
    if (i < total) esrc[i] = dummy_off;
}

// ---------------- fill CSR with byte offsets (src*128), grouped by dst ------------
__global__ void k_fill(const int* __restrict__ src, const int* __restrict__ dst,
                       const int* __restrict__ rowptr, int* __restrict__ cur,
                       int* __restrict__ esrc, int E) {
    int e = blockIdx.x * blockDim.x + threadIdx.x;
    if (e < E) {
        int d = dst[e];
        int p = rowptr[d] + atomicAdd(&cur[d], 1);
        esrc[p] = src[e] << 7;     // byte offset of 128-B bf16 row
    }
}

// ---------------- prep W1: fp32 [512][64] -> bf16 fragment layout -----------------
__global__ void k_prepw(const float* __restrict__ W1, unsigned short* __restrict__ w1f) {
    int f = blockIdx.x * 256 + threadIdx.x;      // 32768 total
    int k = f >> 6, c = f & 63;
    w1f[(((k >> 3) * 64) + c) * 8 + (k & 7)] = f2bf(W1[f]);
}

// ---------------- GEMM1: h1' = bf16(dis[row] * (X @ W1))  ----------------
// 512 thr = 8 waves; block = 128 rows x 64 cols. Depth-2 prefetch ring on X loads.
__launch_bounds__(512, 4)
__global__ void k_gemm1(const float* __restrict__ X, const unsigned short* __restrict__ w1f,
                        const float* __restrict__ dis, unsigned short* __restrict__ h1p,
                        int N) {
    __shared__ __align__(16) unsigned short wlds[IN_CH * MID_CH]; // 64 KB
    {
        const uint4* s4 = (const uint4*)w1f;
        uint4* d4 = (uint4*)wlds;
        #pragma unroll
        for (int i = 0; i < 8; ++i)
            d4[threadIdx.x + i * 512] = s4[threadIdx.x + i * 512];
    }
    __syncthreads();

    int wave = threadIdx.x >> 6, lane = threadIdx.x & 63;
    int rbase = blockIdx.x * 128 + wave * 16;
    int g = lane >> 4;
    int arow = rbase + (lane & 15);
    if (arow > N - 1) arow = N - 1;              // clamp loads; stores are guarded
    const float* xp = X + (size_t)arow * IN_CH + g * 8;

    f32x4 acc[4];
    #pragma unroll
    for (int i = 0; i < 4; ++i) acc[i] = (f32x4){0.f, 0.f, 0.f, 0.f};

    // prefetch ring, depth 2 (all indices compile-time after full unroll)
    float4 bx0[2], bx1[2];
    {
        const float4* p0 = (const float4*)(xp);
        const float4* p1 = (const float4*)(xp + 32);
        bx0[0] = p0[0]; bx1[0] = p0[1];
        bx0[1] = p1[0]; bx1[1] = p1[1];
    }

    #pragma unroll
    for (int ks = 0; ks < 16; ++ks) {
        float4 x0 = bx0[ks & 1], x1 = bx1[ks & 1];
        if (ks < 14) {
            const float4* p = (const float4*)(xp + (ks + 2) * 32);
            bx0[ks & 1] = p[0]; bx1[ks & 1] = p[1];
        }
        short8 a;
        a[0] = (short)f2bf(x0.x); a[1] = (short)f2bf(x0.y);
        a[2] = (short)f2bf(x0.z); a[3] = (short)f2bf(x0.w);
        a[4] = (short)f2bf(x1.x); a[5] = (short)f2bf(x1.y);
        a[6] = (short)f2bf(x1.z); a[7] = (short)f2bf(x1.w);

        int cibase = (ks * 4 + g) * 64 + (lane & 15);
        #pragma unroll
        for (int ct = 0; ct < 4; ++ct) {
            short8 b = *((const short8*)(wlds + (size_t)(cibase + ct * 16) * 8));
            acc[ct] = __builtin_amdgcn_mfma_f32_16x16x32_bf16(a, b, acc[ct], 0, 0, 0);
        }
    }

    // D layout: col = lane&15, row = (lane>>4)*4 + reg
    int colb = lane & 15;
    int rquad = rbase + (lane >> 4) * 4;
    #pragma unroll
    for (int ct = 0; ct < 4; ++ct) {
        #pragma unroll
        for (int r = 0; r < 4; ++r) {
            int row = rquad + r;
            if (row < N)
                h1p[(size_t)row * 64 + ct * 16 + colb] = f2bf(acc[ct][r] * dis[row]);
        }
    }
}

// ---- gather helpers: 4 independent loads in flight per 16-edge block -------------
#define AGG_UNPACK(U)                                   \
    acc[0] += __uint_as_float((U).x << 16);             \
    acc[1] += __uint_as_float((U).x & 0xffff0000u);     \
    acc[2] += __uint_as_float((U).y << 16);             \
    acc[3] += __uint_as_float((U).y & 0xffff0000u);

// ---------------- layer 1: gather + finish + elu (one wave per node) --------------
__launch_bounds__(256)
__global__ void k_agg1(const unsigned short* __restrict__ hp, const float* __restrict__ dis,
                       const int* __restrict__ rowptr, const int* __restrict__ esrc,
                       const float* __restrict__ b1, unsigned short* __restrict__ h2p,
                       int N) {
    int wv = threadIdx.x >> 6, lane = threadIdx.x & 63;
    int n = blockIdx.x * 4 + wv;
    if (n >= N) return;
    int g = lane >> 4, cg = lane & 15;
    int beg = rowptr[n], end = rowptr[n + 1];
    unsigned cgoff = (unsigned)(cg * 8);
    const char* hb = (const char*)hp;

    f32x4 acc = (f32x4){0.f, 0.f, 0.f, 0.f};
    for (int cbeg = beg; cbeg < end; cbeg += 64) {
        int m = end - cbeg; if (m > 64) m = 64;          // multiple of 4
        int soff = esrc[cbeg + lane];
        int k4n = m >> 2;
        int k4 = 0;
        for (; k4 + 4 <= k4n; k4 += 4) {                 // 16 edges, 4 loads in flight
            int o0 = __shfl(soff, (k4 + 0) * 4 + g);
            int o1 = __shfl(soff, (k4 + 1) * 4 + g);
            int o2 = __shfl(soff, (k4 + 2) * 4 + g);
            int o3 = __shfl(soff, (k4 + 3) * 4 + g);
            uint2 u0 = *(const uint2*)(hb + ((unsigned)o0 + cgoff));
            uint2 u1 = *(const uint2*)(hb + ((unsigned)o1 + cgoff));
            uint2 u2 = *(const uint2*)(hb + ((unsigned)o2 + cgoff));
            uint2 u3 = *(const uint2*)(hb + ((unsigned)o3 + cgoff));
            AGG_UNPACK(u0) AGG_UNPACK(u1) AGG_UNPACK(u2) AGG_UNPACK(u3)
        }
        for (; k4 < k4n; ++k4) {
            int o = __shfl(soff, k4 * 4 + g);
            uint2 u = *(const uint2*)(hb + ((unsigned)o + cgoff));
            AGG_UNPACK(u)
        }
    }
    #pragma unroll
    for (int off = 32; off >= 16; off >>= 1) {
        acc[0] += __shfl_xor(acc[0], off);
        acc[1] += __shfl_xor(acc[1], off);
        acc[2] += __shfl_xor(acc[2], off);
        acc[3] += __shfl_xor(acc[3], off);
    }
    if (g == 0) {
        float dn = dis[n];
        uint2 us = *(const uint2*)(hb + ((unsigned)(n * 128) + cgoff));
        float4 b4 = *(const float4*)(b1 + cg * 4);
        float s0 = __uint_as_float(us.x << 16),       s1 = __uint_as_float(us.x & 0xffff0000u);
        float s2 = __uint_as_float(us.y << 16),       s3 = __uint_as_float(us.y & 0xffff0000u);
        float v0 = dn * (acc[0] + s0) + b4.x;
        float v1 = dn * (acc[1] + s1) + b4.y;
        float v2 = dn * (acc[2] + s2) + b4.z;
        float v3 = dn * (acc[3] + s3) + b4.w;
        v0 = v0 > 0.f ? v0 : expm1f(v0);
        v1 = v1 > 0.f ? v1 : expm1f(v1);
        v2 = v2 > 0.f ? v2 : expm1f(v2);
        v3 = v3 > 0.f ? v3 : expm1f(v3);
        uint2 o;
        o.x = (unsigned)f2bf(dn * v0) | ((unsigned)f2bf(dn * v1) << 16);
        o.y = (unsigned)f2bf(dn * v2) | ((unsigned)f2bf(dn * v3) << 16);
        *(uint2*)(h2p + (size_t)n * 64 + cg * 4) = o;
    }
}

// ---------------- layer 2: gather + GEMM2 + log_softmax ---------------------------
__launch_bounds__(256)
__global__ void k_agg2(const unsigned short* __restrict__ hp, const float* __restrict__ dis,
                       const int* __restrict__ rowptr, const int* __restrict__ esrc,
                       const float* __restrict__ W2, const float* __restrict__ b2,
                       float* __restrict__ out, int N) {
    __shared__ float w2l[MID_CH * OUT_CH];
    __shared__ float vl[4 * MID_CH];
    for (int f = threadIdx.x; f < MID_CH * OUT_CH; f += 256) w2l[f] = W2[f];
    __syncthreads();

    int wv = threadIdx.x >> 6, lane = threadIdx.x & 63;
    int n = blockIdx.x * 4 + wv;
    if (n >= N) return;
    int g = lane >> 4, cg = lane & 15;
    int beg = rowptr[n], end = rowptr[n + 1];
    unsigned cgoff = (unsigned)(cg * 8);
    const char* hb = (const char*)hp;

    f32x4 acc = (f32x4){0.f, 0.f, 0.f, 0.f};
    for (int cbeg = beg; cbeg < end; cbeg += 64) {
        int m = end - cbeg; if (m > 64) m = 64;
        int soff = esrc[cbeg + lane];
        int k4n = m >> 2;
        int k4 = 0;
        for (; k4 + 4 <= k4n; k4 += 4) {
            int o0 = __shfl(soff, (k4 + 0) * 4 + g);
            int o1 = __shfl(soff, (k4 + 1) * 4 + g);
            int o2 = __shfl(soff, (k4 + 2) * 4 + g);
            int o3 = __shfl(soff, (k4 + 3) * 4 + g);
            uint2 u0 = *(const uint2*)(hb + ((unsigned)o0 + cgoff));
            uint2 u1 = *(const uint2*)(hb + ((unsigned)o1 + cgoff));
            uint2 u2 = *(const uint2*)(hb + ((unsigned)o2 + cgoff));
            uint2 u3 = *(const uint2*)(hb + ((unsigned)o3 + cgoff));
            AGG_UNPACK(u0) AGG_UNPACK(u1) AGG_UNPACK(u2) AGG_UNPACK(u3)
        }
        for (; k4 < k4n; ++k4) {
            int o = __shfl(soff, k4 * 4 + g);
            uint2 u = *(const uint2*)(hb + ((unsigned)o + cgoff));
            AGG_UNPACK(u)
        }
    }
    #pragma unroll
    for (int off = 32; off >= 16; off >>= 1) {
        acc[0] += __shfl_xor(acc[0], off);
        acc[1] += __shfl_xor(acc[1], off);
        acc[2] += __shfl_xor(acc[2], off);
        acc[3] += __shfl_xor(acc[3], off);
    }
    if (g == 0) {
        float dn = dis[n];
        uint2 us = *(const uint2*)(hb + ((unsigned)(n * 128) + cgoff));
        float4 v;
        v.x = dn * (acc[0] + __uint_as_float(us.x << 16));
        v.y = dn * (acc[1] + __uint_as_float(us.x & 0xffff0000u));
        v.z = dn * (acc[2] + __uint_as_float(us.y << 16));
        v.w = dn * (acc[3] + __uint_as_float(us.y & 0xffff0000u));
        *(float4*)&vl[wv * 64 + cg * 4] = v;
    }

    float o = (lane < OUT_CH) ? b2[lane] : 0.f;
    const float* vrow = &vl[wv * 64];
    #pragma unroll 8
    for (int c = 0; c < MID_CH; ++c)
        o += vrow[c] * w2l[c * OUT_CH + lane];

    float mx = (lane < OUT_CH) ? o : -1e30f;
    #pragma unroll
    for (int off = 32; off > 0; off >>= 1) mx = fmaxf(mx, __shfl_xor(mx, off));
    float e = (lane < OUT_CH) ? expf(o - mx) : 0.f;
    float ssum = e;
    #pragma unroll
    for (int off = 32; off > 0; off >>= 1) ssum += __shfl_xor(ssum, off);
    if (lane < OUT_CH)
        out[(size_t)n * OUT_CH + lane] = o - mx - logf(ssum);
}

extern "C" void kernel_launch(void* const* d_in, const int* in_sizes, int n_in,
                              void* d_out, int out_size, void* d_ws, size_t ws_size,
                              hipStream_t stream) {
    const float* X  = (const float*)d_in[0];
    const int* adj  = (const int*)d_in[1];
    const float* W1 = (const float*)d_in[2];
    const float* b1 = (const float*)d_in[3];
    const float* W2 = (const float*)d_in[4];
    const float* b2 = (const float*)d_in[5];
    float* out = (float*)d_out;

    int N = in_sizes[0] / IN_CH;
    int E = in_sizes[1] / 2;
    const int* srcp = adj;
    const int* dstp = adj + E;
    int nchunk = (N + 1023) / 1024;              // 98 (<=128 required)
    int epad_max = E + 3 * N + 128;

    char* ws = (char*)d_ws;
    size_t off = 0;
    int*   cnt    = (int*)(ws + off);  off += (size_t)N * sizeof(int);        // also cursor
    float* dis    = (float*)(ws + off); off += (size_t)N * sizeof(float);
    int*   rowptr = (int*)(ws + off);  off += ((size_t)N + 8) * sizeof(int);
    int*   bsum   = (int*)(ws + off);  off += 128 * sizeof(int);
    int*   esrc   = (int*)(ws + off);  off += (size_t)epad_max * sizeof(int);
    unsigned short* w1f = (unsigned short*)(ws + off); off += (size_t)IN_CH * MID_CH * sizeof(unsigned short);
    unsigned short* h1p = (unsigned short*)(ws + off); off += (size_t)(N + 2) * MID_CH * sizeof(unsigned short);
    unsigned short* h2p = (unsigned short*)(ws + off); off += (size_t)(N + 2) * MID_CH * sizeof(unsigned short);

    hipMemsetAsync(cnt, 0, (size_t)N * sizeof(int), stream);
    k_prepw<<<(IN_CH * MID_CH + 255) / 256, 256, 0, stream>>>(W1, w1f);
    k_count<<<(E + 255) / 256, 256, 0, stream>>>(dstp, cnt, E);
    k_scanA<<<nchunk, 1024, 0, stream>>>(cnt, rowptr, bsum, dis, N);
    k_scanB<<<1, 128, 0, stream>>>(bsum, nchunk);
    k_scanC<<<nchunk, 1024, 0, stream>>>(rowptr, bsum, N);
    k_padfill<<<(epad_max + 255) / 256, 256, 0, stream>>>(esrc, N << 7, epad_max);
    hipMemsetAsync(cnt, 0, (size_t)N * sizeof(int), stream);  // cursor
    k_fill<<<(E + 255) / 256, 256, 0, stream>>>(srcp, dstp, rowptr, cnt, esrc, E);

    // zero dummy row N of both tables (padded edges point here)
    hipMemsetAsync(h1p + (size_t)N * 64, 0, 128, stream);
    hipMemsetAsync(h2p + (size_t)N * 64, 0, 128, stream);

    k_gemm1<<<(N + 127) / 128, 512, 0, stream>>>(X, w1f, dis, h1p, N);
    k_agg1<<<(N + 3) / 4, 256, 0, stream>>>(h1p, dis, rowptr, esrc, b1, h2p, N);
    k_agg2<<<(N + 3) / 4, 256, 0, stream>>>(h2p, dis, rowptr, esrc, W2, b2, out, N);
}

// Round 6
// 357.268 us; speedup vs baseline: 2.6096x; 1.0744x over previous
//
#include <hip/hip_runtime.h>
#include <hip/hip_bf16.h>
#include <math.h>

#define IN_CH 512
#define MID_CH 64
#define OUT_CH 40

typedef __attribute__((ext_vector_type(8))) short short8;
typedef __attribute__((ext_vector_type(4))) float f32x4;
typedef __attribute__((ext_vector_type(2))) float f32x2;

static __device__ __forceinline__ unsigned short f2bf(float f) {
    unsigned int u = __float_as_uint(f);
    u += 0x7fffu + ((u >> 16) & 1u);   // round-to-nearest-even on bf16 boundary
    return (unsigned short)(u >> 16);
}

// ---------------- degree count ----------------
__global__ void k_count(const int* __restrict__ dst, int* __restrict__ cnt, int E) {
    int i = blockIdx.x * blockDim.x + threadIdx.x;
    if (i < E) atomicAdd(&cnt[dst[i]], 1);
}

// ---------------- CSR scan over PADDED degrees (round up to 4); dis from real deg ---
__global__ void k_scanA(const int* __restrict__ cnt, int* __restrict__ rowptr,
                        int* __restrict__ bsum, float* __restrict__ dis, int N) {
    __shared__ int wsum[16];
    int i = blockIdx.x * 1024 + threadIdx.x;
    int lane = threadIdx.x & 63, wv = threadIdx.x >> 6;
    int v = (i < N) ? cnt[i] : 0;
    if (i < N) dis[i] = rsqrtf((float)v + 1.0f);
    int x = (v + 3) & ~3;                      // padded degree
    #pragma unroll
    for (int off = 1; off < 64; off <<= 1) {
        int t = __shfl_up(x, off);
        if (lane >= off) x += t;
    }
    if (lane == 63) wsum[wv] = x;
    __syncthreads();
    if (wv == 0 && lane < 16) {
        int own = wsum[lane];
        int y = own;
        #pragma unroll
        for (int off = 1; off < 16; off <<= 1) {
            int t = __shfl_up(y, off);
            if (lane >= off) y += t;
        }
        wsum[lane] = y - own;
        if (lane == 15) bsum[blockIdx.x] = y;
    }
    __syncthreads();
    if (i < N) rowptr[i + 1] = x + wsum[wv];
}

__global__ void k_scanB(int* __restrict__ bsum, int nb) {
    __shared__ int tmp[2];
    int lane = threadIdx.x & 63, wv = threadIdx.x >> 6;
    int v = (threadIdx.x < nb) ? bsum[threadIdx.x] : 0;
    int x = v;
    #pragma unroll
    for (int off = 1; off < 64; off <<= 1) {
        int t = __shfl_up(x, off);
        if (lane >= off) x += t;
    }
    if (lane == 63) tmp[wv] = x;
    __syncthreads();
    int add = (wv == 1) ? tmp[0] : 0;
    if (threadIdx.x < nb) bsum[threadIdx.x] = x - v + add;
}

__global__ void k_scanC(int* __restrict__ rowptr, const int* __restrict__ bsum, int N) {
    int i = blockIdx.x * 1024 + threadIdx.x;
    if (i < N) rowptr[i + 1] += bsum[blockIdx.x];
    if (i == 0) rowptr[0] = 0;
}

// ---------------- init padded esrc slots to dummy-row byte offset ----------------
__global__ void k_padfill(int* __restrict__ esrc, int dummy_off, int total) {
    int i = blockIdx.x * blockDim.x + threadIdx.x;
    if (i < total) esrc[i] = dummy_off;
}

// ---------------- fill CSR with byte offsets (src*64), grouped by dst -------------
__global__ void k_fill(const int* __restrict__ src, const int* __restrict__ dst,
                       const int* __restrict__ rowptr, int* __restrict__ cur,
                       int* __restrict__ esrc, int E) {
    int e = blockIdx.x * blockDim.x + threadIdx.x;
    if (e < E) {
        int d = dst[e];
        int p = rowptr[d] + atomicAdd(&cur[d], 1);
        esrc[p] = src[e] << 6;     // byte offset of 64-B fp8 row
    }
}

// ---------------- prep W1: fp32 [512][64] -> bf16 fragment layout -----------------
__global__ void k_prepw(const float* __restrict__ W1, unsigned short* __restrict__ w1f) {
    int f = blockIdx.x * 256 + threadIdx.x;      // 32768 total
    int k = f >> 6, c = f & 63;
    w1f[(((k >> 3) * 64) + c) * 8 + (k & 7)] = f2bf(W1[f]);
}

// ---------------- GEMM1: h1q = fp8(dis[row] * (X @ W1))  ----------------
// 512 thr = 8 waves; block = 128 rows x 64 cols. Depth-2 prefetch ring on X loads.
__launch_bounds__(512, 4)
__global__ void k_gemm1(const float* __restrict__ X, const unsigned short* __restrict__ w1f,
                        const float* __restrict__ dis, unsigned char* __restrict__ h1q,
                        int N) {
    __shared__ __align__(16) unsigned short wlds[IN_CH * MID_CH]; // 64 KB
    {
        const uint4* s4 = (const uint4*)w1f;
        uint4* d4 = (uint4*)wlds;
        #pragma unroll
        for (int i = 0; i < 8; ++i)
            d4[threadIdx.x + i * 512] = s4[threadIdx.x + i * 512];
    }
    __syncthreads();

    int wave = threadIdx.x >> 6, lane = threadIdx.x & 63;
    int rbase = blockIdx.x * 128 + wave * 16;
    int g = lane >> 4;
    int arow = rbase + (lane & 15);
    if (arow > N - 1) arow = N - 1;              // clamp loads; stores are guarded
    const float* xp = X + (size_t)arow * IN_CH + g * 8;

    f32x4 acc[4];
    #pragma unroll
    for (int i = 0; i < 4; ++i) acc[i] = (f32x4){0.f, 0.f, 0.f, 0.f};

    float4 bx0[2], bx1[2];
    {
        const float4* p0 = (const float4*)(xp);
        const float4* p1 = (const float4*)(xp + 32);
        bx0[0] = p0[0]; bx1[0] = p0[1];
        bx0[1] = p1[0]; bx1[1] = p1[1];
    }

    #pragma unroll
    for (int ks = 0; ks < 16; ++ks) {
        float4 x0 = bx0[ks & 1], x1 = bx1[ks & 1];
        if (ks < 14) {
            const float4* p = (const float4*)(xp + (ks + 2) * 32);
            bx0[ks & 1] = p[0]; bx1[ks & 1] = p[1];
        }
        short8 a;
        a[0] = (short)f2bf(x0.x); a[1] = (short)f2bf(x0.y);
        a[2] = (short)f2bf(x0.z); a[3] = (short)f2bf(x0.w);
        a[4] = (short)f2bf(x1.x); a[5] = (short)f2bf(x1.y);
        a[6] = (short)f2bf(x1.z); a[7] = (short)f2bf(x1.w);

        int cibase = (ks * 4 + g) * 64 + (lane & 15);
        #pragma unroll
        for (int ct = 0; ct < 4; ++ct) {
            short8 b = *((const short8*)(wlds + (size_t)(cibase + ct * 16) * 8));
            acc[ct] = __builtin_amdgcn_mfma_f32_16x16x32_bf16(a, b, acc[ct], 0, 0, 0);
        }
    }

    // D layout: col = lane&15, row = (lane>>4)*4 + reg
    int colb = lane & 15;
    int rquad = rbase + (lane >> 4) * 4;
    #pragma unroll
    for (int ct = 0; ct < 4; ++ct) {
        #pragma unroll
        for (int r = 0; r < 4; ++r) {
            int row = rquad + r;
            if (row < N) {
                float v = acc[ct][r] * dis[row];
                unsigned q = __builtin_amdgcn_cvt_pk_fp8_f32(v, v, 0, false);
                h1q[(size_t)row * 64 + ct * 16 + colb] = (unsigned char)q;
            }
        }
    }
}

// ---- fp8 gather unpack: one u32 = 4 channels ----
#define AGG_UNPACK8(Q)                                              \
    {                                                               \
        f32x2 lo_ = __builtin_amdgcn_cvt_pk_f32_fp8((Q), false);    \
        f32x2 hi_ = __builtin_amdgcn_cvt_pk_f32_fp8((Q), true);     \
        acc[0] += lo_[0]; acc[1] += lo_[1];                         \
        acc[2] += hi_[0]; acc[3] += hi_[1];                         \
    }

// ---------------- layer 1: gather + finish + elu (one wave per node) --------------
// lane = (g = lane>>4 edge subgroup, cg = lane&15 channel quad); row = 64B fp8
__launch_bounds__(256)
__global__ void k_agg1(const unsigned char* __restrict__ hq, const float* __restrict__ dis,
                       const int* __restrict__ rowptr, const int* __restrict__ esrc,
                       const float* __restrict__ b1, unsigned char* __restrict__ h2q,
                       int N) {
    int wv = threadIdx.x >> 6, lane = threadIdx.x & 63;
    int n = blockIdx.x * 4 + wv;
    if (n >= N) return;
    int g = lane >> 4, cg = lane & 15;
    int beg = rowptr[n], end = rowptr[n + 1];
    unsigned cgoff = (unsigned)(cg * 4);
    const char* hb = (const char*)hq;

    f32x4 acc = (f32x4){0.f, 0.f, 0.f, 0.f};
    for (int cbeg = beg; cbeg < end; cbeg += 64) {
        int m = end - cbeg; if (m > 64) m = 64;          // multiple of 4
        int soff = esrc[cbeg + lane];
        int k4n = m >> 2;
        int k4 = 0;
        for (; k4 + 4 <= k4n; k4 += 4) {                 // 16 edges, 4 loads in flight
            int o0 = __shfl(soff, (k4 + 0) * 4 + g);
            int o1 = __shfl(soff, (k4 + 1) * 4 + g);
            int o2 = __shfl(soff, (k4 + 2) * 4 + g);
            int o3 = __shfl(soff, (k4 + 3) * 4 + g);
            unsigned q0 = *(const unsigned*)(hb + ((unsigned)o0 + cgoff));
            unsigned q1 = *(const unsigned*)(hb + ((unsigned)o1 + cgoff));
            unsigned q2 = *(const unsigned*)(hb + ((unsigned)o2 + cgoff));
            unsigned q3 = *(const unsigned*)(hb + ((unsigned)o3 + cgoff));
            AGG_UNPACK8(q0) AGG_UNPACK8(q1) AGG_UNPACK8(q2) AGG_UNPACK8(q3)
        }
        for (; k4 < k4n; ++k4) {
            int o = __shfl(soff, k4 * 4 + g);
            unsigned q = *(const unsigned*)(hb + ((unsigned)o + cgoff));
            AGG_UNPACK8(q)
        }
    }
    #pragma unroll
    for (int off = 32; off >= 16; off >>= 1) {
        acc[0] += __shfl_xor(acc[0], off);
        acc[1] += __shfl_xor(acc[1], off);
        acc[2] += __shfl_xor(acc[2], off);
        acc[3] += __shfl_xor(acc[3], off);
    }
    if (g == 0) {
        float dn = dis[n];
        unsigned qs = *(const unsigned*)(hb + ((unsigned)(n * 64) + cgoff));
        f32x2 slo = __builtin_amdgcn_cvt_pk_f32_fp8(qs, false);
        f32x2 shi = __builtin_amdgcn_cvt_pk_f32_fp8(qs, true);
        float4 b4 = *(const float4*)(b1 + cg * 4);
        float v0 = dn * (acc[0] + slo[0]) + b4.x;
        float v1 = dn * (acc[1] + slo[1]) + b4.y;
        float v2 = dn * (acc[2] + shi[0]) + b4.z;
        float v3 = dn * (acc[3] + shi[1]) + b4.w;
        v0 = v0 > 0.f ? v0 : expm1f(v0);
        v1 = v1 > 0.f ? v1 : expm1f(v1);
        v2 = v2 > 0.f ? v2 : expm1f(v2);
        v3 = v3 > 0.f ? v3 : expm1f(v3);
        unsigned w = __builtin_amdgcn_cvt_pk_fp8_f32(dn * v0, dn * v1, 0, false);
        w = __builtin_amdgcn_cvt_pk_fp8_f32(dn * v2, dn * v3, w, true);
        *(unsigned*)(h2q + (size_t)n * 64 + cg * 4) = w;
    }
}

// ---------------- layer 2: gather + GEMM2 + log_softmax ---------------------------
__launch_bounds__(256)
__global__ void k_agg2(const unsigned char* __restrict__ hq, const float* __restrict__ dis,
                       const int* __restrict__ rowptr, const int* __restrict__ esrc,
                       const float* __restrict__ W2, const float* __restrict__ b2,
                       float* __restrict__ out, int N) {
    __shared__ float w2l[MID_CH * OUT_CH];
    __shared__ float vl[4 * MID_CH];
    for (int f = threadIdx.x; f < MID_CH * OUT_CH; f += 256) w2l[f] = W2[f];
    __syncthreads();

    int wv = threadIdx.x >> 6, lane = threadIdx.x & 63;
    int n = blockIdx.x * 4 + wv;
    if (n >= N) return;
    int g = lane >> 4, cg = lane & 15;
    int beg = rowptr[n], end = rowptr[n + 1];
    unsigned cgoff = (unsigned)(cg * 4);
    const char* hb = (const char*)hq;

    f32x4 acc = (f32x4){0.f, 0.f, 0.f, 0.f};
    for (int cbeg = beg; cbeg < end; cbeg += 64) {
        int m = end - cbeg; if (m > 64) m = 64;
        int soff = esrc[cbeg + lane];
        int k4n = m >> 2;
        int k4 = 0;
        for (; k4 + 4 <= k4n; k4 += 4) {
            int o0 = __shfl(soff, (k4 + 0) * 4 + g);
            int o1 = __shfl(soff, (k4 + 1) * 4 + g);
            int o2 = __shfl(soff, (k4 + 2) * 4 + g);
            int o3 = __shfl(soff, (k4 + 3) * 4 + g);
            unsigned q0 = *(const unsigned*)(hb + ((unsigned)o0 + cgoff));
            unsigned q1 = *(const unsigned*)(hb + ((unsigned)o1 + cgoff));
            unsigned q2 = *(const unsigned*)(hb + ((unsigned)o2 + cgoff));
            unsigned q3 = *(const unsigned*)(hb + ((unsigned)o3 + cgoff));
            AGG_UNPACK8(q0) AGG_UNPACK8(q1) AGG_UNPACK8(q2) AGG_UNPACK8(q3)
        }
        for (; k4 < k4n; ++k4) {
            int o = __shfl(soff, k4 * 4 + g);
            unsigned q = *(const unsigned*)(hb + ((unsigned)o + cgoff));
            AGG_UNPACK8(q)
        }
    }
    #pragma unroll
    for (int off = 32; off >= 16; off >>= 1) {
        acc[0] += __shfl_xor(acc[0], off);
        acc[1] += __shfl_xor(acc[1], off);
        acc[2] += __shfl_xor(acc[2], off);
        acc[3] += __shfl_xor(acc[3], off);
    }
    if (g == 0) {
        float dn = dis[n];
        unsigned qs = *(const unsigned*)(hb + ((unsigned)(n * 64) + cgoff));
        f32x2 slo = __builtin_amdgcn_cvt_pk_f32_fp8(qs, false);
        f32x2 shi = __builtin_amdgcn_cvt_pk_f32_fp8(qs, true);
        float4 v;
        v.x = dn * (acc[0] + slo[0]);
        v.y = dn * (acc[1] + slo[1]);
        v.z = dn * (acc[2] + shi[0]);
        v.w = dn * (acc[3] + shi[1]);
        *(float4*)&vl[wv * 64 + cg * 4] = v;
    }

    float o = (lane < OUT_CH) ? b2[lane] : 0.f;
    const float* vrow = &vl[wv * 64];
    #pragma unroll 8
    for (int c = 0; c < MID_CH; ++c)
        o += vrow[c] * w2l[c * OUT_CH + lane];

    float mx = (lane < OUT_CH) ? o : -1e30f;
    #pragma unroll
    for (int off = 32; off > 0; off >>= 1) mx = fmaxf(mx, __shfl_xor(mx, off));
    float e = (lane < OUT_CH) ? expf(o - mx) : 0.f;
    float ssum = e;
    #pragma unroll
    for (int off = 32; off > 0; off >>= 1) ssum += __shfl_xor(ssum, off);
    if (lane < OUT_CH)
        out[(size_t)n * OUT_CH + lane] = o - mx - logf(ssum);
}

extern "C" void kernel_launch(void* const* d_in, const int* in_sizes, int n_in,
                              void* d_out, int out_size, void* d_ws, size_t ws_size,
                              hipStream_t stream) {
    const float* X  = (const float*)d_in[0];
    const int* adj  = (const int*)d_in[1];
    const float* W1 = (const float*)d_in[2];
    const float* b1 = (const float*)d_in[3];
    const float* W2 = (const float*)d_in[4];
    const float* b2 = (const float*)d_in[5];
    float* out = (float*)d_out;

    int N = in_sizes[0] / IN_CH;
    int E = in_sizes[1] / 2;
    const int* srcp = adj;
    const int* dstp = adj + E;
    int nchunk = (N + 1023) / 1024;              // 98 (<=128 required)
    int epad_max = E + 3 * N + 128;

    char* ws = (char*)d_ws;
    size_t off = 0;
    int*   cnt    = (int*)(ws + off);  off += (size_t)N * sizeof(int);        // also cursor
    float* dis    = (float*)(ws + off); off += (size_t)N * sizeof(float);
    int*   rowptr = (int*)(ws + off);  off += ((size_t)N + 8) * sizeof(int);
    int*   bsum   = (int*)(ws + off);  off += 128 * sizeof(int);
    int*   esrc   = (int*)(ws + off);  off += (size_t)epad_max * sizeof(int);
    unsigned short* w1f = (unsigned short*)(ws + off); off += (size_t)IN_CH * MID_CH * sizeof(unsigned short);
    unsigned char* h1q = (unsigned char*)(ws + off); off += (size_t)(N + 4) * MID_CH;
    unsigned char* h2q = (unsigned char*)(ws + off); off += (size_t)(N + 4) * MID_CH;

    hipMemsetAsync(cnt, 0, (size_t)N * sizeof(int), stream);
    k_prepw<<<(IN_CH * MID_CH + 255) / 256, 256, 0, stream>>>(W1, w1f);
    k_count<<<(E + 255) / 256, 256, 0, stream>>>(dstp, cnt, E);
    k_scanA<<<nchunk, 1024, 0, stream>>>(cnt, rowptr, bsum, dis, N);
    k_scanB<<<1, 128, 0, stream>>>(bsum, nchunk);
    k_scanC<<<nchunk, 1024, 0, stream>>>(rowptr, bsum, N);
    k_padfill<<<(epad_max + 255) / 256, 256, 0, stream>>>(esrc, N << 6, epad_max);
    hipMemsetAsync(cnt, 0, (size_t)N * sizeof(int), stream);  // cursor
    k_fill<<<(E + 255) / 256, 256, 0, stream>>>(srcp, dstp, rowptr, cnt, esrc, E);

    // zero dummy row N of both tables (padded edges point here)
    hipMemsetAsync(h1q + (size_t)N * 64, 0, 64, stream);
    hipMemsetAsync(h2q + (size_t)N * 64, 0, 64, stream);

    k_gemm1<<<(N + 127) / 128, 512, 0, stream>>>(X, w1f, dis, h1q, N);
    k_agg1<<<(N + 3) / 4, 256, 0, stream>>>(h1q, dis, rowptr, esrc, b1, h2q, N);
    k_agg2<<<(N + 3) / 4, 256, 0, stream>>>(h2q, dis, rowptr, esrc, W2, b2, out, N);
}

// Round 7
// 345.919 us; speedup vs baseline: 2.6952x; 1.0328x over previous
//
#include <hip/hip_runtime.h>
#include <hip/hip_bf16.h>
#include <math.h>

#define IN_CH 512
#define MID_CH 64
#define OUT_CH 40

typedef __attribute__((ext_vector_type(8))) short short8;
typedef __attribute__((ext_vector_type(4))) float f32x4;
typedef __attribute__((ext_vector_type(2))) float f32x2;

static __device__ __forceinline__ unsigned short f2bf(float f) {
    unsigned int u = __float_as_uint(f);
    u += 0x7fffu + ((u >> 16) & 1u);   // round-to-nearest-even on bf16 boundary
    return (unsigned short)(u >> 16);
}

// ---------------- degree count, partitioned by dst&7 for XCD write locality -------
__global__ void k_count(const int* __restrict__ dst, int* __restrict__ cnt, int E) {
    int pb = blockIdx.x & 7;
    int ch = blockIdx.x >> 3;
    int nch = gridDim.x >> 3;
    int ech = (E + nch - 1) / nch;
    int e0 = ch * ech;
    int e1 = e0 + ech; if (e1 > E) e1 = E;
    for (int e = e0 + threadIdx.x; e < e1; e += blockDim.x) {
        int d = dst[e];
        if ((d & 7) == pb) atomicAdd(&cnt[d], 1);
    }
}

// ---------------- CSR scan over PADDED degrees (round up to 4); dis from real deg ---
__global__ void k_scanA(const int* __restrict__ cnt, int* __restrict__ rowptr,
                        int* __restrict__ bsum, float* __restrict__ dis, int N) {
    __shared__ int wsum[16];
    int i = blockIdx.x * 1024 + threadIdx.x;
    int lane = threadIdx.x & 63, wv = threadIdx.x >> 6;
    int v = (i < N) ? cnt[i] : 0;
    if (i < N) dis[i] = rsqrtf((float)v + 1.0f);
    int x = (v + 3) & ~3;                      // padded degree
    #pragma unroll
    for (int off = 1; off < 64; off <<= 1) {
        int t = __shfl_up(x, off);
        if (lane >= off) x += t;
    }
    if (lane == 63) wsum[wv] = x;
    __syncthreads();
    if (wv == 0 && lane < 16) {
        int own = wsum[lane];
        int y = own;
        #pragma unroll
        for (int off = 1; off < 16; off <<= 1) {
            int t = __shfl_up(y, off);
            if (lane >= off) y += t;
        }
        wsum[lane] = y - own;
        if (lane == 15) bsum[blockIdx.x] = y;
    }
    __syncthreads();
    if (i < N) rowptr[i + 1] = x + wsum[wv];
}

__global__ void k_scanB(int* __restrict__ bsum, int nb) {
    __shared__ int tmp[2];
    int lane = threadIdx.x & 63, wv = threadIdx.x >> 6;
    int v = (threadIdx.x < nb) ? bsum[threadIdx.x] : 0;
    int x = v;
    #pragma unroll
    for (int off = 1; off < 64; off <<= 1) {
        int t = __shfl_up(x, off);
        if (lane >= off) x += t;
    }
    if (lane == 63) tmp[wv] = x;
    __syncthreads();
    int add = (wv == 1) ? tmp[0] : 0;
    if (threadIdx.x < nb) bsum[threadIdx.x] = x - v + add;
}

__global__ void k_scanC(int* __restrict__ rowptr, const int* __restrict__ bsum, int N) {
    int i = blockIdx.x * 1024 + threadIdx.x;
    if (i < N) rowptr[i + 1] += bsum[blockIdx.x];
    if (i == 0) rowptr[0] = 0;
}

// ---------------- init padded esrc slots to dummy-row byte offset ----------------
__global__ void k_padfill(int* __restrict__ esrc, int dummy_off, int total) {
    int i = blockIdx.x * blockDim.x + threadIdx.x;
    if (i < total) esrc[i] = dummy_off;
}

// ---------------- prep W1: fp32 [512][64] -> bf16 fragment layout -----------------
__global__ void k_prepw(const float* __restrict__ W1, unsigned short* __restrict__ w1f) {
    int f = blockIdx.x * 256 + threadIdx.x;      // 32768 total
    int k = f >> 6, c = f & 63;
    w1f[(((k >> 3) * 64) + c) * 8 + (k & 7)] = f2bf(W1[f]);
}

// ---------------- fused: CSR fill (partitioned) + GEMM1, heterogeneous blocks -----
// blocks [0,2*FB): even -> gemm gb=b/2, odd -> fill fb=b/2 ; blocks >=2*FB -> gemm
// fill: partition pb = fb&7 (dst&7 == pb), chunk = fb>>3 of nch = FB/8 chunks
__launch_bounds__(512, 2)
__global__ void k_fillgemm(const float* __restrict__ X, const unsigned short* __restrict__ w1f,
                           const float* __restrict__ dis, unsigned char* __restrict__ h1q,
                           int N, int FB,
                           const int* __restrict__ src, const int* __restrict__ dst,
                           const int* __restrict__ rowptr, int* __restrict__ cur,
                           int* __restrict__ esrc, int E) {
    __shared__ __align__(16) unsigned short wlds[IN_CH * MID_CH]; // 64 KB
    int b = blockIdx.x;
    int gb, fb = -1;
    if (b < 2 * FB) { if (b & 1) { fb = b >> 1; gb = -1; } else gb = b >> 1; }
    else gb = b - FB;

    if (fb >= 0) {
        // ---- fill path ----
        int pb = fb & 7;
        int ch = fb >> 3;
        int nch = FB >> 3;
        int ech = (E + nch - 1) / nch;
        int e0 = ch * ech;
        int e1 = e0 + ech; if (e1 > E) e1 = E;
        for (int e = e0 + (int)threadIdx.x; e < e1; e += 512) {
            int d = dst[e];
            if ((d & 7) == pb) {
                int p = rowptr[d] + atomicAdd(&cur[d], 1);
                esrc[p] = src[e] << 6;
            }
        }
        return;
    }

    // ---- gemm path ----
    {
        const uint4* s4 = (const uint4*)w1f;
        uint4* d4 = (uint4*)wlds;
        #pragma unroll
        for (int i = 0; i < 8; ++i)
            d4[threadIdx.x + i * 512] = s4[threadIdx.x + i * 512];
    }
    __syncthreads();

    int wave = threadIdx.x >> 6, lane = threadIdx.x & 63;
    int rbase = gb * 128 + wave * 16;
    int g = lane >> 4;
    int arow = rbase + (lane & 15);
    if (arow > N - 1) arow = N - 1;              // clamp loads; stores are guarded
    const float* xp = X + (size_t)arow * IN_CH + g * 8;

    f32x4 acc[4];
    #pragma unroll
    for (int i = 0; i < 4; ++i) acc[i] = (f32x4){0.f, 0.f, 0.f, 0.f};

    float4 bx0[2], bx1[2];
    {
        const float4* p0 = (const float4*)(xp);
        const float4* p1 = (const float4*)(xp + 32);
        bx0[0] = p0[0]; bx1[0] = p0[1];
        bx0[1] = p1[0]; bx1[1] = p1[1];
    }

    #pragma unroll
    for (int ks = 0; ks < 16; ++ks) {
        float4 x0 = bx0[ks & 1], x1 = bx1[ks & 1];
        if (ks < 14) {
            const float4* p = (const float4*)(xp + (ks + 2) * 32);
            bx0[ks & 1] = p[0]; bx1[ks & 1] = p[1];
        }
        short8 a;
        a[0] = (short)f2bf(x0.x); a[1] = (short)f2bf(x0.y);
        a[2] = (short)f2bf(x0.z); a[3] = (short)f2bf(x0.w);
        a[4] = (short)f2bf(x1.x); a[5] = (short)f2bf(x1.y);
        a[6] = (short)f2bf(x1.z); a[7] = (short)f2bf(x1.w);

        int cibase = (ks * 4 + g) * 64 + (lane & 15);
        #pragma unroll
        for (int ct = 0; ct < 4; ++ct) {
            short8 bfr = *((const short8*)(wlds + (size_t)(cibase + ct * 16) * 8));
            acc[ct] = __builtin_amdgcn_mfma_f32_16x16x32_bf16(a, bfr, acc[ct], 0, 0, 0);
        }
    }

    // D layout: col = lane&15, row = (lane>>4)*4 + reg
    int colb = lane & 15;
    int rquad = rbase + (lane >> 4) * 4;
    #pragma unroll
    for (int ct = 0; ct < 4; ++ct) {
        #pragma unroll
        for (int r = 0; r < 4; ++r) {
            int row = rquad + r;
            if (row < N) {
                float v = acc[ct][r] * dis[row];
                unsigned q = __builtin_amdgcn_cvt_pk_fp8_f32(v, v, 0, false);
                h1q[(size_t)row * 64 + ct * 16 + colb] = (unsigned char)q;
            }
        }
    }
}

// ---- fp8 gather unpack: one u32 = 4 channels ----
#define AGG_UNPACK8(Q)                                              \
    {                                                               \
        f32x2 lo_ = __builtin_amdgcn_cvt_pk_f32_fp8((Q), false);    \
        f32x2 hi_ = __builtin_amdgcn_cvt_pk_f32_fp8((Q), true);     \
        acc[0] += lo_[0]; acc[1] += lo_[1];                         \
        acc[2] += hi_[0]; acc[3] += hi_[1];                         \
    }

// ---------------- layer 1: gather + finish + elu (one wave per node) --------------
__launch_bounds__(256)
__global__ void k_agg1(const unsigned char* __restrict__ hq, const float* __restrict__ dis,
                       const int* __restrict__ rowptr, const int* __restrict__ esrc,
                       const float* __restrict__ b1, unsigned char* __restrict__ h2q,
                       int N) {
    int wv = threadIdx.x >> 6, lane = threadIdx.x & 63;
    int n = blockIdx.x * 4 + wv;
    if (n >= N) return;
    int g = lane >> 4, cg = lane & 15;
    int beg = rowptr[n], end = rowptr[n + 1];
    unsigned cgoff = (unsigned)(cg * 4);
    const char* hb = (const char*)hq;

    f32x4 acc = (f32x4){0.f, 0.f, 0.f, 0.f};
    for (int cbeg = beg; cbeg < end; cbeg += 64) {
        int m = end - cbeg; if (m > 64) m = 64;          // multiple of 4
        int soff = esrc[cbeg + lane];
        int k4n = m >> 2;
        int k4 = 0;
        for (; k4 + 4 <= k4n; k4 += 4) {                 // 16 edges, 4 loads in flight
            int o0 = __shfl(soff, (k4 + 0) * 4 + g);
            int o1 = __shfl(soff, (k4 + 1) * 4 + g);
            int o2 = __shfl(soff, (k4 + 2) * 4 + g);
            int o3 = __shfl(soff, (k4 + 3) * 4 + g);
            unsigned q0 = *(const unsigned*)(hb + ((unsigned)o0 + cgoff));
            unsigned q1 = *(const unsigned*)(hb + ((unsigned)o1 + cgoff));
            unsigned q2 = *(const unsigned*)(hb + ((unsigned)o2 + cgoff));
            unsigned q3 = *(const unsigned*)(hb + ((unsigned)o3 + cgoff));
            AGG_UNPACK8(q0) AGG_UNPACK8(q1) AGG_UNPACK8(q2) AGG_UNPACK8(q3)
        }
        for (; k4 < k4n; ++k4) {
            int o = __shfl(soff, k4 * 4 + g);
            unsigned q = *(const unsigned*)(hb + ((unsigned)o + cgoff));
            AGG_UNPACK8(q)
        }
    }
    #pragma unroll
    for (int off = 32; off >= 16; off >>= 1) {
        acc[0] += __shfl_xor(acc[0], off);
        acc[1] += __shfl_xor(acc[1], off);
        acc[2] += __shfl_xor(acc[2], off);
        acc[3] += __shfl_xor(acc[3], off);
    }
    if (g == 0) {
        float dn = dis[n];
        unsigned qs = *(const unsigned*)(hb + ((unsigned)(n * 64) + cgoff));
        f32x2 slo = __builtin_amdgcn_cvt_pk_f32_fp8(qs, false);
        f32x2 shi = __builtin_amdgcn_cvt_pk_f32_fp8(qs, true);
        float4 b4 = *(const float4*)(b1 + cg * 4);
        float v0 = dn * (acc[0] + slo[0]) + b4.x;
        float v1 = dn * (acc[1] + slo[1]) + b4.y;
        float v2 = dn * (acc[2] + shi[0]) + b4.z;
        float v3 = dn * (acc[3] + shi[1]) + b4.w;
        v0 = v0 > 0.f ? v0 : expm1f(v0);
        v1 = v1 > 0.f ? v1 : expm1f(v1);
        v2 = v2 > 0.f ? v2 : expm1f(v2);
        v3 = v3 > 0.f ? v3 : expm1f(v3);
        unsigned w = __builtin_amdgcn_cvt_pk_fp8_f32(dn * v0, dn * v1, 0, false);
        w = __builtin_amdgcn_cvt_pk_fp8_f32(dn * v2, dn * v3, w, true);
        *(unsigned*)(h2q + (size_t)n * 64 + cg * 4) = w;
    }
}

// ---------------- layer 2: gather + GEMM2 + log_softmax ---------------------------
__launch_bounds__(256)
__global__ void k_agg2(const unsigned char* __restrict__ hq, const float* __restrict__ dis,
                       const int* __restrict__ rowptr, const int* __restrict__ esrc,
                       const float* __restrict__ W2, const float* __restrict__ b2,
                       float* __restrict__ out, int N) {
    __shared__ float w2l[MID_CH * OUT_CH];
    __shared__ float vl[4 * MID_CH];
    for (int f = threadIdx.x; f < MID_CH * OUT_CH; f += 256) w2l[f] = W2[f];
    __syncthreads();

    int wv = threadIdx.x >> 6, lane = threadIdx.x & 63;
    int n = blockIdx.x * 4 + wv;
    if (n >= N) return;
    int g = lane >> 4, cg = lane & 15;
    int beg = rowptr[n], end = rowptr[n + 1];
    unsigned cgoff = (unsigned)(cg * 4);
    const char* hb = (const char*)hq;

    f32x4 acc = (f32x4){0.f, 0.f, 0.f, 0.f};
    for (int cbeg = beg; cbeg < end; cbeg += 64) {
        int m = end - cbeg; if (m > 64) m = 64;
        int soff = esrc[cbeg + lane];
        int k4n = m >> 2;
        int k4 = 0;
        for (; k4 + 4 <= k4n; k4 += 4) {
            int o0 = __shfl(soff, (k4 + 0) * 4 + g);
            int o1 = __shfl(soff, (k4 + 1) * 4 + g);
            int o2 = __shfl(soff, (k4 + 2) * 4 + g);
            int o3 = __shfl(soff, (k4 + 3) * 4 + g);
            unsigned q0 = *(const unsigned*)(hb + ((unsigned)o0 + cgoff));
            unsigned q1 = *(const unsigned*)(hb + ((unsigned)o1 + cgoff));
            unsigned q2 = *(const unsigned*)(hb + ((unsigned)o2 + cgoff));
            unsigned q3 = *(const unsigned*)(hb + ((unsigned)o3 + cgoff));
            AGG_UNPACK8(q0) AGG_UNPACK8(q1) AGG_UNPACK8(q2) AGG_UNPACK8(q3)
        }
        for (; k4 < k4n; ++k4) {
            int o = __shfl(soff, k4 * 4 + g);
            unsigned q = *(const unsigned*)(hb + ((unsigned)o + cgoff));
            AGG_UNPACK8(q)
        }
    }
    #pragma unroll
    for (int off = 32; off >= 16; off >>= 1) {
        acc[0] += __shfl_xor(acc[0], off);
        acc[1] += __shfl_xor(acc[1], off);
        acc[2] += __shfl_xor(acc[2], off);
        acc[3] += __shfl_xor(acc[3], off);
    }
    if (g == 0) {
        float dn = dis[n];
        unsigned qs = *(const unsigned*)(hb + ((unsigned)(n * 64) + cgoff));
        f32x2 slo = __builtin_amdgcn_cvt_pk_f32_fp8(qs, false);
        f32x2 shi = __builtin_amdgcn_cvt_pk_f32_fp8(qs, true);
        float4 v;
        v.x = dn * (acc[0] + slo[0]);
        v.y = dn * (acc[1] + slo[1]);
        v.z = dn * (acc[2] + shi[0]);
        v.w = dn * (acc[3] + shi[1]);
        *(float4*)&vl[wv * 64 + cg * 4] = v;
    }

    float o = (lane < OUT_CH) ? b2[lane] : 0.f;
    const float* vrow = &vl[wv * 64];
    #pragma unroll 8
    for (int c = 0; c < MID_CH; ++c)
        o += vrow[c] * w2l[c * OUT_CH + lane];

    float mx = (lane < OUT_CH) ? o : -1e30f;
    #pragma unroll
    for (int off = 32; off > 0; off >>= 1) mx = fmaxf(mx, __shfl_xor(mx, off));
    float e = (lane < OUT_CH) ? expf(o - mx) : 0.f;
    float ssum = e;
    #pragma unroll
    for (int off = 32; off > 0; off >>= 1) ssum += __shfl_xor(ssum, off);
    if (lane < OUT_CH)
        out[(size_t)n * OUT_CH + lane] = o - mx - logf(ssum);
}

extern "C" void kernel_launch(void* const* d_in, const int* in_sizes, int n_in,
                              void* d_out, int out_size, void* d_ws, size_t ws_size,
                              hipStream_t stream) {
    const float* X  = (const float*)d_in[0];
    const int* adj  = (const int*)d_in[1];
    const float* W1 = (const float*)d_in[2];
    const float* b1 = (const float*)d_in[3];
    const float* W2 = (const float*)d_in[4];
    const float* b2 = (const float*)d_in[5];
    float* out = (float*)d_out;

    int N = in_sizes[0] / IN_CH;
    int E = in_sizes[1] / 2;
    const int* srcp = adj;
    const int* dstp = adj + E;
    int nchunk = (N + 1023) / 1024;              // 98 (<=128 required)
    int epad_max = E + 3 * N + 128;
    int GB = (N + 127) / 128;                    // gemm blocks (782)
    int FB = 512;                                // fill blocks (must be mult of 8)

    char* ws = (char*)d_ws;
    size_t off = 0;
    int*   cnt    = (int*)(ws + off);  off += (size_t)N * sizeof(int);        // also cursor
    float* dis    = (float*)(ws + off); off += (size_t)N * sizeof(float);
    int*   rowptr = (int*)(ws + off);  off += ((size_t)N + 8) * sizeof(int);
    int*   bsum   = (int*)(ws + off);  off += 128 * sizeof(int);
    int*   esrc   = (int*)(ws + off);  off += (size_t)epad_max * sizeof(int);
    unsigned short* w1f = (unsigned short*)(ws + off); off += (size_t)IN_CH * MID_CH * sizeof(unsigned short);
    unsigned char* h1q = (unsigned char*)(ws + off); off += (size_t)(N + 4) * MID_CH;
    unsigned char* h2q = (unsigned char*)(ws + off); off += (size_t)(N + 4) * MID_CH;

    hipMemsetAsync(cnt, 0, (size_t)N * sizeof(int), stream);
    k_prepw<<<(IN_CH * MID_CH + 255) / 256, 256, 0, stream>>>(W1, w1f);
    k_count<<<512, 256, 0, stream>>>(dstp, cnt, E);
    k_scanA<<<nchunk, 1024, 0, stream>>>(cnt, rowptr, bsum, dis, N);
    k_scanB<<<1, 128, 0, stream>>>(bsum, nchunk);
    k_scanC<<<nchunk, 1024, 0, stream>>>(rowptr, bsum, N);
    k_padfill<<<(epad_max + 255) / 256, 256, 0, stream>>>(esrc, N << 6, epad_max);
    hipMemsetAsync(cnt, 0, (size_t)N * sizeof(int), stream);  // cursor
    // zero dummy row N of both tables (padded edges point here)
    hipMemsetAsync(h1q + (size_t)N * 64, 0, 64, stream);
    hipMemsetAsync(h2q + (size_t)N * 64, 0, 64, stream);

    k_fillgemm<<<GB + FB, 512, 0, stream>>>(X, w1f, dis, h1q, N, FB,
                                            srcp, dstp, rowptr, cnt, esrc, E);
    k_agg1<<<(N + 3) / 4, 256, 0, stream>>>(h1q, dis, rowptr, esrc, b1, h2q, N);
    k_agg2<<<(N + 3) / 4, 256, 0, stream>>>(h2q, dis, rowptr, esrc, W2, b2, out, N);
}

// Round 8
// 336.932 us; speedup vs baseline: 2.7671x; 1.0267x over previous
//
#include <hip/hip_runtime.h>
#include <hip/hip_bf16.h>
#include <math.h>

#define IN_CH 512
#define MID_CH 64
#define OUT_CH 40

typedef __attribute__((ext_vector_type(8))) short short8;
typedef __attribute__((ext_vector_type(4))) float f32x4;
typedef __attribute__((ext_vector_type(2))) float f32x2;

static __device__ __forceinline__ unsigned short f2bf(float f) {
    unsigned int u = __float_as_uint(f);
    u += 0x7fffu + ((u >> 16) & 1u);   // round-to-nearest-even on bf16 boundary
    return (unsigned short)(u >> 16);
}

// ---------------- degree count, partitioned by dst&7 (pb == blockIdx&7 -> XCD) ----
__global__ void k_count(const int* __restrict__ dst, int* __restrict__ cnt, int E) {
    int pb = blockIdx.x & 7;
    int ch = blockIdx.x >> 3;
    int nch = gridDim.x >> 3;
    int ech = (E + nch - 1) / nch;
    int e0 = ch * ech;
    int e1 = e0 + ech; if (e1 > E) e1 = E;
    for (int e = e0 + threadIdx.x; e < e1; e += blockDim.x) {
        int d = dst[e];
        if ((d & 7) == pb) atomicAdd(&cnt[d], 1);
    }
}

// ---------------- CSR scan over PADDED degrees (round up to 4); dis from real deg ---
__global__ void k_scanA(const int* __restrict__ cnt, int* __restrict__ rowptr,
                        int* __restrict__ bsum, float* __restrict__ dis, int N) {
    __shared__ int wsum[16];
    int i = blockIdx.x * 1024 + threadIdx.x;
    int lane = threadIdx.x & 63, wv = threadIdx.x >> 6;
    int v = (i < N) ? cnt[i] : 0;
    if (i < N) dis[i] = rsqrtf((float)v + 1.0f);
    int x = (v + 3) & ~3;                      // padded degree
    #pragma unroll
    for (int off = 1; off < 64; off <<= 1) {
        int t = __shfl_up(x, off);
        if (lane >= off) x += t;
    }
    if (lane == 63) wsum[wv] = x;
    __syncthreads();
    if (wv == 0 && lane < 16) {
        int own = wsum[lane];
        int y = own;
        #pragma unroll
        for (int off = 1; off < 16; off <<= 1) {
            int t = __shfl_up(y, off);
            if (lane >= off) y += t;
        }
        wsum[lane] = y - own;
        if (lane == 15) bsum[blockIdx.x] = y;
    }
    __syncthreads();
    if (i < N) rowptr[i + 1] = x + wsum[wv];
}

__global__ void k_scanB(int* __restrict__ bsum, int nb) {
    __shared__ int tmp[2];
    int lane = threadIdx.x & 63, wv = threadIdx.x >> 6;
    int v = (threadIdx.x < nb) ? bsum[threadIdx.x] : 0;
    int x = v;
    #pragma unroll
    for (int off = 1; off < 64; off <<= 1) {
        int t = __shfl_up(x, off);
        if (lane >= off) x += t;
    }
    if (lane == 63) tmp[wv] = x;
    __syncthreads();
    int add = (wv == 1) ? tmp[0] : 0;
    if (threadIdx.x < nb) bsum[threadIdx.x] = x - v + add;
}

// C: add chunk offsets; ALSO initialize cursor cur[] = rowptr[]
__global__ void k_scanC(int* __restrict__ rowptr, int* __restrict__ cur,
                        const int* __restrict__ bsum, int N) {
    int i = blockIdx.x * 1024 + threadIdx.x;
    if (i < N) {
        int v = rowptr[i + 1] + bsum[blockIdx.x];
        rowptr[i + 1] = v;
        cur[i + 1] = v;
    }
    if (i == 0) { rowptr[0] = 0; cur[0] = 0; }
}

// ---------------- init padded esrc slots to dummy-row byte offset ----------------
__global__ void k_padfill(int* __restrict__ esrc, int dummy_off, int total) {
    int i = blockIdx.x * blockDim.x + threadIdx.x;
    if (i < total) esrc[i] = dummy_off;
}

// ---------------- fill CSR (partitioned by dst&7, cursor pre-seeded) --------------
__global__ void k_fill(const int* __restrict__ src, const int* __restrict__ dst,
                       int* __restrict__ cur, int* __restrict__ esrc, int E) {
    int pb = blockIdx.x & 7;
    int ch = blockIdx.x >> 3;
    int nch = gridDim.x >> 3;
    int ech = (E + nch - 1) / nch;
    int e0 = ch * ech;
    int e1 = e0 + ech; if (e1 > E) e1 = E;
    #pragma unroll 4
    for (int e = e0 + (int)threadIdx.x; e < e1; e += blockDim.x) {
        int d = dst[e];
        if ((d & 7) == pb) {
            int p = atomicAdd(&cur[d], 1);
            esrc[p] = src[e] << 6;      // byte offset of 64-B fp8 row
        }
    }
}

// ---------------- prep W1: fp32 [512][64] -> bf16 fragment layout -----------------
// layout: w1f[((k>>3)*64 + c)*8 + (k&7)] : 16B per (k-chunk, col) fragment
__global__ void k_prepw(const float* __restrict__ W1, unsigned short* __restrict__ w1f) {
    int f = blockIdx.x * 256 + threadIdx.x;      // 32768 total
    int k = f >> 6, c = f & 63;
    w1f[(((k >> 3) * 64) + c) * 8 + (k & 7)] = f2bf(W1[f]);
}

// ---------------- GEMM1: h1q = fp8(dis[row] * (X @ W1)), no LDS -------------------
// 256 thr = 4 waves; block = 64 rows x 64 cols. B-frags read direct from w1f
// (64 KB, L1/L2-resident, coalesced 16B/lane). Depth-2 prefetch ring on X.
__launch_bounds__(256, 6)
__global__ void k_gemm1(const float* __restrict__ X, const unsigned short* __restrict__ w1f,
                        const float* __restrict__ dis, unsigned char* __restrict__ h1q,
                        int N) {
    int wave = threadIdx.x >> 6, lane = threadIdx.x & 63;
    int rbase = blockIdx.x * 64 + wave * 16;
    int g = lane >> 4;
    int arow = rbase + (lane & 15);
    if (arow > N - 1) arow = N - 1;              // clamp loads; stores are guarded
    const float* xp = X + (size_t)arow * IN_CH + g * 8;
    const short8* wb = (const short8*)w1f;

    f32x4 acc[4];
    #pragma unroll
    for (int i = 0; i < 4; ++i) acc[i] = (f32x4){0.f, 0.f, 0.f, 0.f};

    float4 bx0[2], bx1[2];
    {
        const float4* p0 = (const float4*)(xp);
        const float4* p1 = (const float4*)(xp + 32);
        bx0[0] = p0[0]; bx1[0] = p0[1];
        bx0[1] = p1[0]; bx1[1] = p1[1];
    }

    #pragma unroll
    for (int ks = 0; ks < 16; ++ks) {
        float4 x0 = bx0[ks & 1], x1 = bx1[ks & 1];
        if (ks < 14) {
            const float4* p = (const float4*)(xp + (ks + 2) * 32);
            bx0[ks & 1] = p[0]; bx1[ks & 1] = p[1];
        }
        short8 a;
        a[0] = (short)f2bf(x0.x); a[1] = (short)f2bf(x0.y);
        a[2] = (short)f2bf(x0.z); a[3] = (short)f2bf(x0.w);
        a[4] = (short)f2bf(x1.x); a[5] = (short)f2bf(x1.y);
        a[6] = (short)f2bf(x1.z); a[7] = (short)f2bf(x1.w);

        int cibase = (ks * 4 + g) * 64 + (lane & 15);
        #pragma unroll
        for (int ct = 0; ct < 4; ++ct) {
            short8 b = wb[cibase + ct * 16];
            acc[ct] = __builtin_amdgcn_mfma_f32_16x16x32_bf16(a, b, acc[ct], 0, 0, 0);
        }
    }

    // D layout: col = lane&15, row = (lane>>4)*4 + reg
    int colb = lane & 15;
    int rquad = rbase + (lane >> 4) * 4;
    #pragma unroll
    for (int ct = 0; ct < 4; ++ct) {
        #pragma unroll
        for (int r = 0; r < 4; ++r) {
            int row = rquad + r;
            if (row < N) {
                float v = acc[ct][r] * dis[row];
                unsigned q = __builtin_amdgcn_cvt_pk_fp8_f32(v, v, 0, false);
                h1q[(size_t)row * 64 + ct * 16 + colb] = (unsigned char)q;
            }
        }
    }
}

// ---- fp8 gather unpack: one u32 = 4 channels ----
#define AGG_UNPACK8(Q)                                              \
    {                                                               \
        f32x2 lo_ = __builtin_amdgcn_cvt_pk_f32_fp8((Q), false);    \
        f32x2 hi_ = __builtin_amdgcn_cvt_pk_f32_fp8((Q), true);     \
        acc[0] += lo_[0]; acc[1] += lo_[1];                         \
        acc[2] += hi_[0]; acc[3] += hi_[1];                         \
    }

// ---------------- layer 1: gather + finish + elu (one wave per node) --------------
__launch_bounds__(256)
__global__ void k_agg1(const unsigned char* __restrict__ hq, const float* __restrict__ dis,
                       const int* __restrict__ rowptr, const int* __restrict__ esrc,
                       const float* __restrict__ b1, unsigned char* __restrict__ h2q,
                       int N) {
    int wv = threadIdx.x >> 6, lane = threadIdx.x & 63;
    int n = blockIdx.x * 4 + wv;
    if (n >= N) return;
    int g = lane >> 4, cg = lane & 15;
    int beg = rowptr[n], end = rowptr[n + 1];
    unsigned cgoff = (unsigned)(cg * 4);
    const char* hb = (const char*)hq;

    f32x4 acc = (f32x4){0.f, 0.f, 0.f, 0.f};
    for (int cbeg = beg; cbeg < end; cbeg += 64) {
        int m = end - cbeg; if (m > 64) m = 64;          // multiple of 4
        int soff = esrc[cbeg + lane];
        int k4n = m >> 2;
        int k4 = 0;
        for (; k4 + 4 <= k4n; k4 += 4) {                 // 16 edges, 4 loads in flight
            int o0 = __shfl(soff, (k4 + 0) * 4 + g);
            int o1 = __shfl(soff, (k4 + 1) * 4 + g);
            int o2 = __shfl(soff, (k4 + 2) * 4 + g);
            int o3 = __shfl(soff, (k4 + 3) * 4 + g);
            unsigned q0 = *(const unsigned*)(hb + ((unsigned)o0 + cgoff));
            unsigned q1 = *(const unsigned*)(hb + ((unsigned)o1 + cgoff));
            unsigned q2 = *(const unsigned*)(hb + ((unsigned)o2 + cgoff));
            unsigned q3 = *(const unsigned*)(hb + ((unsigned)o3 + cgoff));
            AGG_UNPACK8(q0) AGG_UNPACK8(q1) AGG_UNPACK8(q2) AGG_UNPACK8(q3)
        }
        for (; k4 < k4n; ++k4) {
            int o = __shfl(soff, k4 * 4 + g);
            unsigned q = *(const unsigned*)(hb + ((unsigned)o + cgoff));
            AGG_UNPACK8(q)
        }
    }
    #pragma unroll
    for (int off = 32; off >= 16; off >>= 1) {
        acc[0] += __shfl_xor(acc[0], off);
        acc[1] += __shfl_xor(acc[1], off);
        acc[2] += __shfl_xor(acc[2], off);
        acc[3] += __shfl_xor(acc[3], off);
    }
    if (g == 0) {
        float dn = dis[n];
        unsigned qs = *(const unsigned*)(hb + ((unsigned)(n * 64) + cgoff));
        f32x2 slo = __builtin_amdgcn_cvt_pk_f32_fp8(qs, false);
        f32x2 shi = __builtin_amdgcn_cvt_pk_f32_fp8(qs, true);
        float4 b4 = *(const float4*)(b1 + cg * 4);
        float v0 = dn * (acc[0] + slo[0]) + b4.x;
        float v1 = dn * (acc[1] + slo[1]) + b4.y;
        float v2 = dn * (acc[2] + shi[0]) + b4.z;
        float v3 = dn * (acc[3] + shi[1]) + b4.w;
        v0 = v0 > 0.f ? v0 : expm1f(v0);
        v1 = v1 > 0.f ? v1 : expm1f(v1);
        v2 = v2 > 0.f ? v2 : expm1f(v2);
        v3 = v3 > 0.f ? v3 : expm1f(v3);
        unsigned w = __builtin_amdgcn_cvt_pk_fp8_f32(dn * v0, dn * v1, 0, false);
        w = __builtin_amdgcn_cvt_pk_fp8_f32(dn * v2, dn * v3, w, true);
        *(unsigned*)(h2q + (size_t)n * 64 + cg * 4) = w;
    }
}

// ---------------- layer 2: gather + GEMM2 + log_softmax ---------------------------
__launch_bounds__(256)
__global__ void k_agg2(const unsigned char* __restrict__ hq, const float* __restrict__ dis,
                       const int* __restrict__ rowptr, const int* __restrict__ esrc,
                       const float* __restrict__ W2, const float* __restrict__ b2,
                       float* __restrict__ out, int N) {
    __shared__ float w2l[MID_CH * OUT_CH];
    __shared__ float vl[4 * MID_CH];
    for (int f = threadIdx.x; f < MID_CH * OUT_CH; f += 256) w2l[f] = W2[f];
    __syncthreads();

    int wv = threadIdx.x >> 6, lane = threadIdx.x & 63;
    int n = blockIdx.x * 4 + wv;
    if (n >= N) return;
    int g = lane >> 4, cg = lane & 15;
    int beg = rowptr[n], end = rowptr[n + 1];
    unsigned cgoff = (unsigned)(cg * 4);
    const char* hb = (const char*)hq;

    f32x4 acc = (f32x4){0.f, 0.f, 0.f, 0.f};
    for (int cbeg = beg; cbeg < end; cbeg += 64) {
        int m = end - cbeg; if (m > 64) m = 64;
        int soff = esrc[cbeg + lane];
        int k4n = m >> 2;
        int k4 = 0;
        for (; k4 + 4 <= k4n; k4 += 4) {
            int o0 = __shfl(soff, (k4 + 0) * 4 + g);
            int o1 = __shfl(soff, (k4 + 1) * 4 + g);
            int o2 = __shfl(soff, (k4 + 2) * 4 + g);
            int o3 = __shfl(soff, (k4 + 3) * 4 + g);
            unsigned q0 = *(const unsigned*)(hb + ((unsigned)o0 + cgoff));
            unsigned q1 = *(const unsigned*)(hb + ((unsigned)o1 + cgoff));
            unsigned q2 = *(const unsigned*)(hb + ((unsigned)o2 + cgoff));
            unsigned q3 = *(const unsigned*)(hb + ((unsigned)o3 + cgoff));
            AGG_UNPACK8(q0) AGG_UNPACK8(q1) AGG_UNPACK8(q2) AGG_UNPACK8(q3)
        }
        for (; k4 < k4n; ++k4) {
            int o = __shfl(soff, k4 * 4 + g);
            unsigned q = *(const unsigned*)(hb + ((unsigned)o + cgoff));
            AGG_UNPACK8(q)
        }
    }
    #pragma unroll
    for (int off = 32; off >= 16; off >>= 1) {
        acc[0] += __shfl_xor(acc[0], off);
        acc[1] += __shfl_xor(acc[1], off);
        acc[2] += __shfl_xor(acc[2], off);
        acc[3] += __shfl_xor(acc[3], off);
    }
    if (g == 0) {
        float dn = dis[n];
        unsigned qs = *(const unsigned*)(hb + ((unsigned)(n * 64) + cgoff));
        f32x2 slo = __builtin_amdgcn_cvt_pk_f32_fp8(qs, false);
        f32x2 shi = __builtin_amdgcn_cvt_pk_f32_fp8(qs, true);
        float4 v;
        v.x = dn * (acc[0] + slo[0]);
        v.y = dn * (acc[1] + slo[1]);
        v.z = dn * (acc[2] + shi[0]);
        v.w = dn * (acc[3] + shi[1]);
        *(float4*)&vl[wv * 64 + cg * 4] = v;
    }

    float o = (lane < OUT_CH) ? b2[lane] : 0.f;
    const float* vrow = &vl[wv * 64];
    #pragma unroll 8
    for (int c = 0; c < MID_CH; ++c)
        o += vrow[c] * w2l[c * OUT_CH + lane];

    float mx = (lane < OUT_CH) ? o : -1e30f;
    #pragma unroll
    for (int off = 32; off > 0; off >>= 1) mx = fmaxf(mx, __shfl_xor(mx, off));
    float e = (lane < OUT_CH) ? expf(o - mx) : 0.f;
    float ssum = e;
    #pragma unroll
    for (int off = 32; off > 0; off >>= 1) ssum += __shfl_xor(ssum, off);
    if (lane < OUT_CH)
        out[(size_t)n * OUT_CH + lane] = o - mx - logf(ssum);
}

extern "C" void kernel_launch(void* const* d_in, const int* in_sizes, int n_in,
                              void* d_out, int out_size, void* d_ws, size_t ws_size,
                              hipStream_t stream) {
    const float* X  = (const float*)d_in[0];
    const int* adj  = (const int*)d_in[1];
    const float* W1 = (const float*)d_in[2];
    const float* b1 = (const float*)d_in[3];
    const float* W2 = (const float*)d_in[4];
    const float* b2 = (const float*)d_in[5];
    float* out = (float*)d_out;

    int N = in_sizes[0] / IN_CH;
    int E = in_sizes[1] / 2;
    const int* srcp = adj;
    const int* dstp = adj + E;
    int nchunk = (N + 1023) / 1024;              // 98 (<=128 required)
    int epad_max = E + 3 * N + 128;

    char* ws = (char*)d_ws;
    size_t off = 0;
    int*   cnt    = (int*)(ws + off);  off += (size_t)N * sizeof(int);
    int*   cur    = (int*)(ws + off);  off += ((size_t)N + 8) * sizeof(int);
    float* dis    = (float*)(ws + off); off += (size_t)N * sizeof(float);
    int*   rowptr = (int*)(ws + off);  off += ((size_t)N + 8) * sizeof(int);
    int*   bsum   = (int*)(ws + off);  off += 128 * sizeof(int);
    int*   esrc   = (int*)(ws + off);  off += (size_t)epad_max * sizeof(int);
    unsigned short* w1f = (unsigned short*)(ws + off); off += (size_t)IN_CH * MID_CH * sizeof(unsigned short);
    unsigned char* h1q = (unsigned char*)(ws + off); off += (size_t)(N + 4) * MID_CH;
    unsigned char* h2q = (unsigned char*)(ws + off); off += (size_t)(N + 4) * MID_CH;

    hipMemsetAsync(cnt, 0, (size_t)N * sizeof(int), stream);
    k_prepw<<<(IN_CH * MID_CH + 255) / 256, 256, 0, stream>>>(W1, w1f);
    k_count<<<512, 256, 0, stream>>>(dstp, cnt, E);
    k_scanA<<<nchunk, 1024, 0, stream>>>(cnt, rowptr, bsum, dis, N);
    k_scanB<<<1, 128, 0, stream>>>(bsum, nchunk);
    k_scanC<<<nchunk, 1024, 0, stream>>>(rowptr, cur, bsum, N);
    k_padfill<<<(epad_max + 255) / 256, 256, 0, stream>>>(esrc, N << 6, epad_max);
    // zero dummy row N of both tables (padded edges point here)
    hipMemsetAsync(h1q + (size_t)N * 64, 0, 64, stream);
    hipMemsetAsync(h2q + (size_t)N * 64, 0, 64, stream);

    k_fill<<<1024, 256, 0, stream>>>(srcp, dstp, cur, esrc, E);
    k_gemm1<<<(N + 63) / 64, 256, 0, stream>>>(X, w1f, dis, h1q, N);
    k_agg1<<<(N + 3) / 4, 256, 0, stream>>>(h1q, dis, rowptr, esrc, b1, h2q, N);
    k_agg2<<<(N + 3) / 4, 256, 0, stream>>>(h2q, dis, rowptr, esrc, W2, b2, out, N);
}